// Round 3
// baseline (503.564 us; speedup 1.0000x reference)
//
#include <hip/hip_runtime.h>
#include <hip/hip_bf16.h>

// Problem constants
constexpr int kB   = 2;
constexpr int kS   = 2048;
constexpr int kD   = 1024;
constexpr int kH   = 16;
constexpr int kDh  = 64;
constexpr int kBS  = kB * kS;          // 4096 rows

typedef __attribute__((ext_vector_type(8))) short short8;   // 8 bf16 = 4 VGPRs
typedef __attribute__((ext_vector_type(4))) float floatx4;  // MFMA acc

__device__ inline unsigned short f2b(float f) {
    __hip_bfloat16 h = __float2bfloat16(f);
    return *reinterpret_cast<unsigned short*>(&h);
}

__device__ inline floatx4 mfma16(short8 a, short8 b, floatx4 c) {
    return __builtin_amdgcn_mfma_f32_16x16x32_bf16(a, b, c, 0, 0, 0);
}

// async global->LDS, 16B per lane; LDS dest = wave-uniform base + lane*16
__device__ inline void gload16(const unsigned short* g, unsigned short* l) {
    __builtin_amdgcn_global_load_lds(
        (const __attribute__((address_space(1))) void*)g,
        (__attribute__((address_space(3))) void*)l, 16, 0, 0);
}

// ---------------------------------------------------------------------------
// K0: fp32 -> bf16 conversion of x (4M elems) and the 4 weights (4 x 1M elems)
// ---------------------------------------------------------------------------
__global__ void convert_kernel(const float* __restrict__ x,
                               const float* __restrict__ wq, const float* __restrict__ wk,
                               const float* __restrict__ wv, const float* __restrict__ wo,
                               unsigned short* __restrict__ xb, unsigned short* __restrict__ wb) {
    int gid = blockIdx.x * blockDim.x + threadIdx.x;
    long i4 = (long)gid * 4;
    const float* src;
    unsigned short* dst;
    long off;
    if (i4 < (long)kBS * kD) {
        src = x; dst = xb; off = i4;
    } else {
        long w = i4 - (long)kBS * kD;
        int sel = (int)(w >> 20);
        off = w & 1048575;
        src = (sel == 0) ? wq : (sel == 1) ? wk : (sel == 2) ? wv : wo;
        dst = wb + (long)sel * 1048576;
    }
    float4 v = *(const float4*)(src + off);
    ushort4 o;
    o.x = f2b(v.x); o.y = f2b(v.y); o.z = f2b(v.z); o.w = f2b(v.w);
    *(ushort4*)(dst + off) = o;
}

// ---------------------------------------------------------------------------
// K1: NT GEMM  C[M,N] = A[M,K] @ B[N,K]^T   (bf16 in, fp32 accum)
// m97-style staging: global_load_lds width=16, unpadded LDS with XOR-swizzled
// k-chunk: lds chunk (row, j) holds global k-chunk j^(row&3) -> frag ds_read
// conflicts drop 8-way -> 4-way without breaking lane-contiguous LDS dest.
// MODE 0: bf16 C; z==0 (Q) scaled by 1/sqrt(Dh). MODE 1: fp32 C + residual.
// ---------------------------------------------------------------------------
template <int MODE>
__launch_bounds__(256, 2)
__global__ void gemm_nt(const unsigned short* __restrict__ A,
                        const unsigned short* __restrict__ Bw,
                        void* __restrict__ Cout,
                        const float* __restrict__ resid,
                        int M, int N, int K) {
    __shared__ __align__(16) unsigned short As[128 * 32];
    __shared__ __align__(16) unsigned short Bs[128 * 32];

    const int z  = blockIdx.z;
    const unsigned short* Bp = Bw + (size_t)z * N * K;
    const int m0 = blockIdx.y * 128, n0 = blockIdx.x * 128;
    const int tid  = threadIdx.x;
    const int lane = tid & 63, wv = tid >> 6;
    const int wm = wv >> 1, wn = wv & 1;
    const int quad = lane >> 4, l16 = lane & 15;

    floatx4 acc[4][4] = {};

    // staging: thread's two 16B chunks per matrix; chunk c -> row c>>2,
    // global k-chunk (c&3)^(row&3)
    const int c0 = wv * 64 + lane;          // 0..255   (rows 0..63)
    const int c1 = 256 + c0;                // 256..511 (rows 64..127)
    const int ar0 = c0 >> 2, aj0 = ((c0 & 3) ^ (ar0 & 3)) * 8;
    const int ar1 = c1 >> 2, aj1 = ((c1 & 3) ^ (ar1 & 3)) * 8;
    const unsigned short* Ag0 = A  + (size_t)(m0 + ar0) * K + aj0;
    const unsigned short* Ag1 = A  + (size_t)(m0 + ar1) * K + aj1;
    const unsigned short* Bg0 = Bp + (size_t)(n0 + ar0) * K + aj0;
    const unsigned short* Bg1 = Bp + (size_t)(n0 + ar1) * K + aj1;
    unsigned short* Asd0 = As + wv * 512;
    unsigned short* Asd1 = As + (4 + wv) * 512;
    unsigned short* Bsd0 = Bs + wv * 512;
    unsigned short* Bsd1 = Bs + (4 + wv) * 512;

    for (int k0 = 0; k0 < K; k0 += 32) {
        __syncthreads();                    // prior iteration's frag reads done
        gload16(Ag0 + k0, Asd0);
        gload16(Ag1 + k0, Asd1);
        gload16(Bg0 + k0, Bsd0);
        gload16(Bg1 + k0, Bsd1);
        __syncthreads();                    // staging visible (vmcnt drained)

        short8 af[4], bf[4];
#pragma unroll
        for (int i = 0; i < 4; i++) {
            const int R = wm * 64 + i * 16 + l16;
            af[i] = *(const short8*)(As + R * 32 + (quad ^ (l16 & 3)) * 8);
        }
#pragma unroll
        for (int j = 0; j < 4; j++) {
            const int R = wn * 64 + j * 16 + l16;
            bf[j] = *(const short8*)(Bs + R * 32 + (quad ^ (l16 & 3)) * 8);
        }
#pragma unroll
        for (int i = 0; i < 4; i++)
#pragma unroll
            for (int j = 0; j < 4; j++)
                acc[i][j] = mfma16(af[i], bf[j], acc[i][j]);
    }

#pragma unroll
    for (int i = 0; i < 4; i++)
#pragma unroll
        for (int j = 0; j < 4; j++) {
            const int row = m0 + wm * 64 + i * 16 + quad * 4;
            const int col = n0 + wn * 64 + j * 16 + l16;
#pragma unroll
            for (int r = 0; r < 4; r++) {
                float v = acc[i][j][r];
                if (MODE == 0) {
                    if (z == 0) v *= 0.125f;   // fold attention scale into Q
                    ((unsigned short*)Cout)[(size_t)z * M * N + (size_t)(row + r) * N + col] = f2b(v);
                } else {
                    size_t idx = (size_t)(row + r) * N + col;
                    ((float*)Cout)[idx] = v + resid[idx];
                }
            }
        }
}

// ---------------------------------------------------------------------------
// K2: partial column-softmax denominators. psum[z][bh][k] = sum over half the
// q range of exp(s[q,k]). 2048 blocks (100% occupancy), 2 q-tiles per iter.
// ---------------------------------------------------------------------------
__launch_bounds__(256, 8)
__global__ void stats_kernel(const unsigned short* __restrict__ Qb,
                             const unsigned short* __restrict__ Kb,
                             float* __restrict__ psum) {
    const int bh = blockIdx.y;
    const int half = blockIdx.z;
    const int b = bh >> 4, h = bh & 15;
    const int tid = threadIdx.x, lane = tid & 63, w = tid >> 6;
    const int quad = lane >> 4, l16 = lane & 15;
    const int key = blockIdx.x * 64 + w * 16 + l16;

    const unsigned short* Krow = Kb + (size_t)(b * kS + key) * kD + h * kDh;
    short8 bk0 = *(const short8*)(Krow + quad * 8);
    short8 bk1 = *(const short8*)(Krow + 32 + quad * 8);

    const unsigned short* Qbase = Qb + (size_t)(b * kS) * kD + h * kDh;
    const int qstart = half * (kS / 2);
    float l = 0.f;
    for (int q0 = qstart; q0 < qstart + kS / 2; q0 += 32) {
        const unsigned short* Qr0 = Qbase + (size_t)(q0 + l16) * kD;
        const unsigned short* Qr1 = Qbase + (size_t)(q0 + 16 + l16) * kD;
        short8 a0 = *(const short8*)(Qr0 + quad * 8);
        short8 a1 = *(const short8*)(Qr0 + 32 + quad * 8);
        short8 a2 = *(const short8*)(Qr1 + quad * 8);
        short8 a3 = *(const short8*)(Qr1 + 32 + quad * 8);
        floatx4 s0 = {0.f, 0.f, 0.f, 0.f}, s1 = {0.f, 0.f, 0.f, 0.f};
        s0 = mfma16(a0, bk0, s0);
        s1 = mfma16(a2, bk0, s1);
        s0 = mfma16(a1, bk1, s0);
        s1 = mfma16(a3, bk1, s1);
        l += __expf(s0[0]) + __expf(s0[1]) + __expf(s0[2]) + __expf(s0[3]);
        l += __expf(s1[0]) + __expf(s1[1]) + __expf(s1[2]) + __expf(s1[3]);
    }
    l += __shfl_xor(l, 16, 64);
    l += __shfl_xor(l, 32, 64);
    if (quad == 0) psum[(size_t)half * 32 * kS + (size_t)bh * kS + key] = l;
}

// K2c: invl = 1 / (psum0 + psum1)
__global__ void invl_kernel(const float* __restrict__ psum, float* __restrict__ invl) {
    int i = blockIdx.x * 256 + threadIdx.x;   // 65536 total
    invl[i] = 1.0f / (psum[i] + psum[32 * kS + i]);
}

// ---------------------------------------------------------------------------
// K2b: VT[bh][d][k] = V[b][k][h*64+d] * invl[bh][k]   (pre-scaled V^T)
// ---------------------------------------------------------------------------
__global__ void vt_kernel(const unsigned short* __restrict__ Vb,
                          const float* __restrict__ invl,
                          unsigned short* __restrict__ VT) {
    __shared__ unsigned short tile[64 * 65];
    const int bh = blockIdx.y, b = bh >> 4, h = bh & 15;
    const int k0 = blockIdx.x * 64;
    const int tid = threadIdx.x;
    const int kr = tid >> 2, dc = (tid & 3) * 16;

    const float iv = invl[(size_t)bh * kS + k0 + kr];
    const unsigned short* src = Vb + (size_t)(b * kS + k0 + kr) * kD + h * kDh + dc;
    uint4 v0 = *(const uint4*)(src);
    uint4 v1 = *(const uint4*)(src + 8);
    unsigned short vs[16];
    *(uint4*)(vs) = v0; *(uint4*)(vs + 8) = v1;
#pragma unroll
    for (int i = 0; i < 16; i++) {
        __hip_bfloat16 hv = *reinterpret_cast<__hip_bfloat16*>(&vs[i]);
        tile[kr * 65 + dc + i] = f2b(__bfloat162float(hv) * iv);
    }
    __syncthreads();
    const int d = tid >> 2, kc = (tid & 3) * 16;
    unsigned short os[16];
#pragma unroll
    for (int j = 0; j < 16; j++) os[j] = tile[(kc + j) * 65 + d];
    unsigned short* dst = VT + (size_t)bh * kDh * kS + (size_t)d * kS + k0 + kc;
    *(uint4*)(dst)     = *(uint4*)(os);
    *(uint4*)(dst + 8) = *(uint4*)(os + 8);
}

// ---------------------------------------------------------------------------
// K3: ctx = exp(S) @ VT^T, barrier-free, 16 q/wave, 1024 blocks (50% occ).
// K-chunk = 64 keys: 8 S-MFMAs -> exp -> P to own LDS region (swizzled) ->
// 8 PV-MFMAs vs global VT. Next chunk's K frags prefetched before exp/PV.
// ---------------------------------------------------------------------------
__launch_bounds__(256, 2)
__global__ void ctx_kernel(const unsigned short* __restrict__ Qb,
                           const unsigned short* __restrict__ Kb,
                           const unsigned short* __restrict__ VT,
                           unsigned short* __restrict__ Ctx) {
    constexpr int LDP = 72;
    __shared__ __align__(16) unsigned short Pt[4][16 * LDP];

    const int bh = blockIdx.y;
    const int b = bh >> 4, h = bh & 15;
    const int tid = threadIdx.x, lane = tid & 63, w = tid >> 6;
    const int quad = lane >> 4, l16 = lane & 15;
    const int qbase = blockIdx.x * 64 + w * 16;

    const unsigned short* Qrow = Qb + (size_t)(b * kS + qbase + l16) * kD + h * kDh;
    short8 aq0 = *(const short8*)(Qrow + quad * 8);
    short8 aq1 = *(const short8*)(Qrow + 32 + quad * 8);

    floatx4 acc[4] = {};

    const unsigned short* Kbase = Kb + (size_t)(b * kS) * kD + h * kDh;
    const unsigned short* VTb   = VT + (size_t)bh * kDh * kS;
    unsigned short* P = Pt[w];
    const int sw_w = quad * 16;          // write swizzle: ((row>>2)&3)*16
    const int sw_r = (l16 >> 2) * 16;    // read  swizzle

    short8 bk[4][2];
#pragma unroll
    for (int c = 0; c < 4; c++) {
        const unsigned short* Krow = Kbase + (size_t)(c * 16 + l16) * kD;
        bk[c][0] = *(const short8*)(Krow + quad * 8);
        bk[c][1] = *(const short8*)(Krow + 32 + quad * 8);
    }

    for (int k0 = 0; k0 < kS; k0 += 64) {
        // S tiles
        floatx4 sc[4];
#pragma unroll
        for (int c = 0; c < 4; c++) {
            floatx4 t = {0.f, 0.f, 0.f, 0.f};
            t = mfma16(aq0, bk[c][0], t);
            sc[c] = mfma16(aq1, bk[c][1], t);
        }
        // prefetch next chunk's K frags (overlaps exp/LDS/PV)
        const int kn = (k0 + 64 < kS) ? k0 + 64 : 0;
        short8 nbk[4][2];
#pragma unroll
        for (int c = 0; c < 4; c++) {
            const unsigned short* Krow = Kbase + (size_t)(kn + c * 16 + l16) * kD;
            nbk[c][0] = *(const short8*)(Krow + quad * 8);
            nbk[c][1] = *(const short8*)(Krow + 32 + quad * 8);
        }
        // exp -> P (own region, no barrier)
#pragma unroll
        for (int c = 0; c < 4; c++)
#pragma unroll
            for (int r = 0; r < 4; r++)
                P[(quad * 4 + r) * LDP + ((c * 16 + l16) ^ sw_w)] = f2b(__expf(sc[c][r]));

        // PV: A-frags from own P region, B-frags from global VT
        short8 ap0 = *(const short8*)(P + l16 * LDP + ((quad * 8) ^ sw_r));
        short8 ap1 = *(const short8*)(P + l16 * LDP + ((32 + quad * 8) ^ sw_r));
#pragma unroll
        for (int t = 0; t < 4; t++) {
            const unsigned short* Vrow = VTb + (size_t)(t * 16 + l16) * kS + k0;
            acc[t] = mfma16(ap0, *(const short8*)(Vrow + quad * 8), acc[t]);
            acc[t] = mfma16(ap1, *(const short8*)(Vrow + 32 + quad * 8), acc[t]);
        }
#pragma unroll
        for (int c = 0; c < 4; c++) { bk[c][0] = nbk[c][0]; bk[c][1] = nbk[c][1]; }
    }

#pragma unroll
    for (int t = 0; t < 4; t++)
#pragma unroll
        for (int r = 0; r < 4; r++)
            Ctx[(size_t)(b * kS + qbase + quad * 4 + r) * kD + h * kDh + t * 16 + l16] =
                f2b(acc[t][r]);
}

// ---------------------------------------------------------------------------
// K4: row LayerNorm
// ---------------------------------------------------------------------------
__global__ void ln_kernel(const float* __restrict__ R, const float* __restrict__ gamma,
                          const float* __restrict__ beta, float* __restrict__ out) {
    const int row = blockIdx.x;
    const int tid = threadIdx.x;
    const float4 v = ((const float4*)(R + (size_t)row * kD))[tid];
    float s  = v.x + v.y + v.z + v.w;
    float ss = v.x * v.x + v.y * v.y + v.z * v.z + v.w * v.w;
#pragma unroll
    for (int off = 32; off > 0; off >>= 1) {
        s  += __shfl_down(s, off, 64);
        ss += __shfl_down(ss, off, 64);
    }
    __shared__ float ws_s[4], ws_ss[4];
    __shared__ float mu_sh, inv_sh;
    const int lane = tid & 63, w = tid >> 6;
    if (lane == 0) { ws_s[w] = s; ws_ss[w] = ss; }
    __syncthreads();
    if (tid == 0) {
        float S1 = ws_s[0] + ws_s[1] + ws_s[2] + ws_s[3];
        float S2 = ws_ss[0] + ws_ss[1] + ws_ss[2] + ws_ss[3];
        float mu = S1 * (1.0f / kD);
        float var = S2 * (1.0f / kD) - mu * mu;
        mu_sh = mu;
        inv_sh = rsqrtf(var + 1e-5f);
    }
    __syncthreads();
    const float mu = mu_sh, inv = inv_sh;
    const float4 g  = ((const float4*)gamma)[tid];
    const float4 bb = ((const float4*)beta)[tid];
    float4 o;
    o.x = (v.x - mu) * inv * g.x + bb.x;
    o.y = (v.y - mu) * inv * g.y + bb.y;
    o.z = (v.z - mu) * inv * g.z + bb.z;
    o.w = (v.w - mu) * inv * g.w + bb.w;
    ((float4*)(out + (size_t)row * kD))[tid] = o;
}

// ---------------------------------------------------------------------------
// Workspace layout (64.25 MB peak, aliasing is stream-ordered-safe):
//   [0,   8MB)  Xb   bf16 [4096,1024]; REUSED as psum (512KB fp32) after the
//               QKV GEMM consumes Xb (stats runs strictly later).
//   [8,  16MB)  Wb   bf16 wq|wk|wv|wo
//   [16, 40MB)  QKV  bf16 Q|K|V  (Q pre-scaled by 0.125)
//   [40, 48MB)  Ctx  bf16 [4096,1024]
//   [48, 64MB)  VT   bf16 [32][64][2048]; ALIASES R (gemm_nt<1> writes R
//               after ctx's last VT read)
//   [64MB, +256KB) invl fp32 [32,2048]
// ---------------------------------------------------------------------------
extern "C" void kernel_launch(void* const* d_in, const int* in_sizes, int n_in,
                              void* d_out, int out_size, void* d_ws, size_t ws_size,
                              hipStream_t stream) {
    const float* x     = (const float*)d_in[0];
    const float* wq    = (const float*)d_in[1];
    const float* wk    = (const float*)d_in[2];
    const float* wv    = (const float*)d_in[3];
    const float* wo    = (const float*)d_in[4];
    const float* gamma = (const float*)d_in[5];
    const float* beta  = (const float*)d_in[6];
    float* out = (float*)d_out;

    char* ws = (char*)d_ws;
    unsigned short* Xb  = (unsigned short*)(ws);
    float*          psum = (float*)(ws);               // reuses Xb region
    unsigned short* Wb  = (unsigned short*)(ws + (8u  << 20));
    unsigned short* QKV = (unsigned short*)(ws + (16u << 20));
    unsigned short* Qb  = QKV;
    unsigned short* Kb  = QKV + (size_t)kBS * kD;
    unsigned short* Vb  = QKV + (size_t)2 * kBS * kD;
    unsigned short* Ctx = (unsigned short*)(ws + (40u << 20));
    unsigned short* VT  = (unsigned short*)(ws + (48u << 20));
    float* R            = (float*)(ws + (48u << 20));  // aliases VT
    float* invl         = (float*)(ws + (64u << 20));

    convert_kernel<<<8192, 256, 0, stream>>>(x, wq, wk, wv, wo, Xb, Wb);

    gemm_nt<0><<<dim3(kD / 128, kBS / 128, 3), 256, 0, stream>>>(
        Xb, Wb, QKV, nullptr, kBS, kD, kD);

    stats_kernel<<<dim3(kS / 64, kB * kH, 2), 256, 0, stream>>>(Qb, Kb, psum);

    invl_kernel<<<(32 * kS) / 256, 256, 0, stream>>>(psum, invl);

    vt_kernel<<<dim3(kS / 64, kB * kH), 256, 0, stream>>>(Vb, invl, VT);

    ctx_kernel<<<dim3(kS / 64, kB * kH), 256, 0, stream>>>(Qb, Kb, VT, Ctx);

    gemm_nt<1><<<dim3(kD / 128, kBS / 128, 1), 256, 0, stream>>>(
        Ctx, Wb + (size_t)3 * kD * kD, R, x, kBS, kD, kD);

    ln_kernel<<<kBS, 256, 0, stream>>>(R, gamma, beta, out);
}

// Round 4
// 351.094 us; speedup vs baseline: 1.4343x; 1.4343x over previous
//
#include <hip/hip_runtime.h>
#include <hip/hip_bf16.h>

// Problem constants
constexpr int kB   = 2;
constexpr int kS   = 2048;
constexpr int kD   = 1024;
constexpr int kH   = 16;
constexpr int kDh  = 64;
constexpr int kBS  = kB * kS;          // 4096 rows

typedef __attribute__((ext_vector_type(8))) short short8;   // 8 bf16 = 4 VGPRs
typedef __attribute__((ext_vector_type(4))) float floatx4;  // MFMA acc

__device__ inline unsigned short f2b(float f) {
    __hip_bfloat16 h = __float2bfloat16(f);
    return *reinterpret_cast<unsigned short*>(&h);
}

__device__ inline floatx4 mfma16(short8 a, short8 b, floatx4 c) {
    return __builtin_amdgcn_mfma_f32_16x16x32_bf16(a, b, c, 0, 0, 0);
}

// async global->LDS, 16B per lane; LDS dest = wave-uniform base + lane*16
__device__ inline void gload16(const unsigned short* g, unsigned short* l) {
    __builtin_amdgcn_global_load_lds(
        (const __attribute__((address_space(1))) void*)g,
        (__attribute__((address_space(3))) void*)l, 16, 0, 0);
}

// ---------------------------------------------------------------------------
// K0: fp32 -> bf16 conversion of x (4M elems) and the 4 weights (4 x 1M elems)
// ---------------------------------------------------------------------------
__global__ void convert_kernel(const float* __restrict__ x,
                               const float* __restrict__ wq, const float* __restrict__ wk,
                               const float* __restrict__ wv, const float* __restrict__ wo,
                               unsigned short* __restrict__ xb, unsigned short* __restrict__ wb) {
    int gid = blockIdx.x * blockDim.x + threadIdx.x;
    long i4 = (long)gid * 4;
    const float* src;
    unsigned short* dst;
    long off;
    if (i4 < (long)kBS * kD) {
        src = x; dst = xb; off = i4;
    } else {
        long w = i4 - (long)kBS * kD;
        int sel = (int)(w >> 20);
        off = w & 1048575;
        src = (sel == 0) ? wq : (sel == 1) ? wk : (sel == 2) ? wv : wo;
        dst = wb + (long)sel * 1048576;
    }
    float4 v = *(const float4*)(src + off);
    ushort4 o;
    o.x = f2b(v.x); o.y = f2b(v.y); o.z = f2b(v.z); o.w = f2b(v.w);
    *(ushort4*)(dst + off) = o;
}

// ---------------------------------------------------------------------------
// K1: NT GEMM  C[M,N] = A[M,K] @ B[N,K]^T   (bf16 in, fp32 accum)
// m97-style staging: global_load_lds width=16, XOR-swizzled k-chunks.
// MODE 0: bf16 C; z==0 (Q) scaled by 0.125*log2(e) (attention scale folded,
//         exp2 domain). MODE 1: fp32 C + residual.
// ---------------------------------------------------------------------------
template <int MODE>
__launch_bounds__(256, 2)
__global__ void gemm_nt(const unsigned short* __restrict__ A,
                        const unsigned short* __restrict__ Bw,
                        void* __restrict__ Cout,
                        const float* __restrict__ resid,
                        int M, int N, int K) {
    __shared__ __align__(16) unsigned short As[128 * 32];
    __shared__ __align__(16) unsigned short Bs[128 * 32];

    const int z  = blockIdx.z;
    const unsigned short* Bp = Bw + (size_t)z * N * K;
    const int m0 = blockIdx.y * 128, n0 = blockIdx.x * 128;
    const int tid  = threadIdx.x;
    const int lane = tid & 63, wv = tid >> 6;
    const int wm = wv >> 1, wn = wv & 1;
    const int quad = lane >> 4, l16 = lane & 15;

    floatx4 acc[4][4] = {};

    const int c0 = wv * 64 + lane;          // 0..255   (rows 0..63)
    const int c1 = 256 + c0;                // 256..511 (rows 64..127)
    const int ar0 = c0 >> 2, aj0 = ((c0 & 3) ^ (ar0 & 3)) * 8;
    const int ar1 = c1 >> 2, aj1 = ((c1 & 3) ^ (ar1 & 3)) * 8;
    const unsigned short* Ag0 = A  + (size_t)(m0 + ar0) * K + aj0;
    const unsigned short* Ag1 = A  + (size_t)(m0 + ar1) * K + aj1;
    const unsigned short* Bg0 = Bp + (size_t)(n0 + ar0) * K + aj0;
    const unsigned short* Bg1 = Bp + (size_t)(n0 + ar1) * K + aj1;
    unsigned short* Asd0 = As + wv * 512;
    unsigned short* Asd1 = As + (4 + wv) * 512;
    unsigned short* Bsd0 = Bs + wv * 512;
    unsigned short* Bsd1 = Bs + (4 + wv) * 512;

    for (int k0 = 0; k0 < K; k0 += 32) {
        __syncthreads();
        gload16(Ag0 + k0, Asd0);
        gload16(Ag1 + k0, Asd1);
        gload16(Bg0 + k0, Bsd0);
        gload16(Bg1 + k0, Bsd1);
        __syncthreads();

        short8 af[4], bf[4];
#pragma unroll
        for (int i = 0; i < 4; i++) {
            const int R = wm * 64 + i * 16 + l16;
            af[i] = *(const short8*)(As + R * 32 + (quad ^ (l16 & 3)) * 8);
        }
#pragma unroll
        for (int j = 0; j < 4; j++) {
            const int R = wn * 64 + j * 16 + l16;
            bf[j] = *(const short8*)(Bs + R * 32 + (quad ^ (l16 & 3)) * 8);
        }
#pragma unroll
        for (int i = 0; i < 4; i++)
#pragma unroll
            for (int j = 0; j < 4; j++)
                acc[i][j] = mfma16(af[i], bf[j], acc[i][j]);
    }

#pragma unroll
    for (int i = 0; i < 4; i++)
#pragma unroll
        for (int j = 0; j < 4; j++) {
            const int row = m0 + wm * 64 + i * 16 + quad * 4;
            const int col = n0 + wn * 64 + j * 16 + l16;
#pragma unroll
            for (int r = 0; r < 4; r++) {
                float v = acc[i][j][r];
                if (MODE == 0) {
                    if (z == 0) v *= 0.18033688f;   // 0.125 * log2(e): exp2 domain
                    ((unsigned short*)Cout)[(size_t)z * M * N + (size_t)(row + r) * N + col] = f2b(v);
                } else {
                    size_t idx = (size_t)(row + r) * N + col;
                    ((float*)Cout)[idx] = v + resid[idx];
                }
            }
        }
}

// ---------------------------------------------------------------------------
// K2: partial column-softmax denominators (exp2 domain, Q pre-scaled).
// psum[z][bh][k] = sum over quarter q-range of exp2(s[q,k]). 4096 blocks.
// ---------------------------------------------------------------------------
__launch_bounds__(256, 8)
__global__ void stats_kernel(const unsigned short* __restrict__ Qb,
                             const unsigned short* __restrict__ Kb,
                             float* __restrict__ psum) {
    const int bh = blockIdx.y;
    const int part = blockIdx.z;
    const int b = bh >> 4, h = bh & 15;
    const int tid = threadIdx.x, lane = tid & 63, w = tid >> 6;
    const int quad = lane >> 4, l16 = lane & 15;
    const int key = blockIdx.x * 64 + w * 16 + l16;

    const unsigned short* Krow = Kb + (size_t)(b * kS + key) * kD + h * kDh;
    short8 bk0 = *(const short8*)(Krow + quad * 8);
    short8 bk1 = *(const short8*)(Krow + 32 + quad * 8);

    const unsigned short* Qbase = Qb + (size_t)(b * kS) * kD + h * kDh;
    const int qstart = part * (kS / 4);
    float l = 0.f;
    for (int q0 = qstart; q0 < qstart + kS / 4; q0 += 32) {
        const unsigned short* Qr0 = Qbase + (size_t)(q0 + l16) * kD;
        const unsigned short* Qr1 = Qbase + (size_t)(q0 + 16 + l16) * kD;
        short8 a0 = *(const short8*)(Qr0 + quad * 8);
        short8 a1 = *(const short8*)(Qr0 + 32 + quad * 8);
        short8 a2 = *(const short8*)(Qr1 + quad * 8);
        short8 a3 = *(const short8*)(Qr1 + 32 + quad * 8);
        floatx4 s0 = {0.f, 0.f, 0.f, 0.f}, s1 = {0.f, 0.f, 0.f, 0.f};
        s0 = mfma16(a0, bk0, s0);
        s1 = mfma16(a2, bk0, s1);
        s0 = mfma16(a1, bk1, s0);
        s1 = mfma16(a3, bk1, s1);
        l += exp2f(s0[0]) + exp2f(s0[1]) + exp2f(s0[2]) + exp2f(s0[3]);
        l += exp2f(s1[0]) + exp2f(s1[1]) + exp2f(s1[2]) + exp2f(s1[3]);
    }
    l += __shfl_xor(l, 16, 64);
    l += __shfl_xor(l, 32, 64);
    if (quad == 0) psum[(size_t)part * 32 * kS + (size_t)bh * kS + key] = l;
}

// K2c: invl = 1 / (sum of 4 partials)
__global__ void invl_kernel(const float* __restrict__ psum, float* __restrict__ invl) {
    int i = blockIdx.x * 256 + threadIdx.x;   // 65536 total
    invl[i] = 1.0f / (psum[i] + psum[32 * kS + i] + psum[2 * 32 * kS + i] + psum[3 * 32 * kS + i]);
}

// ---------------------------------------------------------------------------
// K2b: VT[bh][d][k] = V[b][k][h*64+d] * invl[bh][k]   (pre-scaled V^T)
// ---------------------------------------------------------------------------
__global__ void vt_kernel(const unsigned short* __restrict__ Vb,
                          const float* __restrict__ invl,
                          unsigned short* __restrict__ VT) {
    __shared__ unsigned short tile[64 * 65];
    const int bh = blockIdx.y, b = bh >> 4, h = bh & 15;
    const int k0 = blockIdx.x * 64;
    const int tid = threadIdx.x;
    const int kr = tid >> 2, dc = (tid & 3) * 16;

    const float iv = invl[(size_t)bh * kS + k0 + kr];
    const unsigned short* src = Vb + (size_t)(b * kS + k0 + kr) * kD + h * kDh + dc;
    uint4 v0 = *(const uint4*)(src);
    uint4 v1 = *(const uint4*)(src + 8);
    unsigned short vs[16];
    *(uint4*)(vs) = v0; *(uint4*)(vs + 8) = v1;
#pragma unroll
    for (int i = 0; i < 16; i++) {
        __hip_bfloat16 hv = *reinterpret_cast<__hip_bfloat16*>(&vs[i]);
        tile[kr * 65 + dc + i] = f2b(__bfloat162float(hv) * iv);
    }
    __syncthreads();
    const int d = tid >> 2, kc = (tid & 3) * 16;
    unsigned short os[16];
#pragma unroll
    for (int j = 0; j < 16; j++) os[j] = tile[(kc + j) * 65 + d];
    unsigned short* dst = VT + (size_t)bh * kDh * kS + (size_t)d * kS + k0 + kc;
    *(uint4*)(dst)     = *(uint4*)(os);
    *(uint4*)(dst + 8) = *(uint4*)(os + 8);
}

// ---------------------------------------------------------------------------
// K3: ctx = exp2(S) @ VT^T — m97-style block staging.
// Block = 128 threads (2 waves x 32 q); grid (32, 32) = 1024 blocks.
// Per 64-key chunk: stage K-tile (64x64) + VT-tile (64x64) into LDS via
// global_load_lds w=16 (8-chunk XOR swizzle -> b128 frag reads at the 8-phase
// bank floor), then per wave: 16 S-MFMA -> exp2 -> P (own LDS region,
// stride-72 swizzle) -> 16 PV-MFMA. Two barriers per chunk; 4 blocks/CU
// co-resident hide the drain.
// ---------------------------------------------------------------------------
__launch_bounds__(128, 3)
__global__ void ctx_kernel(const unsigned short* __restrict__ Qb,
                           const unsigned short* __restrict__ Kb,
                           const unsigned short* __restrict__ VT,
                           unsigned short* __restrict__ Ctx) {
    constexpr int LDP = 72;
    __shared__ __align__(16) unsigned short Ks[64 * 64];
    __shared__ __align__(16) unsigned short VTs[64 * 64];
    __shared__ __align__(16) unsigned short Pt[2][32 * LDP];

    const int bh = blockIdx.y;
    const int b = bh >> 4, h = bh & 15;
    const int tid = threadIdx.x, lane = tid & 63, w = tid >> 6;   // w = 0..1
    const int quad = lane >> 4, l16 = lane & 15;
    const int qbase = blockIdx.x * 64 + w * 32;

    // Q fragments (2 q-tiles x 2 d-halves), held in regs
    short8 aq[2][2];
#pragma unroll
    for (int s = 0; s < 2; s++) {
        const unsigned short* Qrow = Qb + (size_t)(b * kS + qbase + s * 16 + l16) * kD + h * kDh;
        aq[s][0] = *(const short8*)(Qrow + quad * 8);
        aq[s][1] = *(const short8*)(Qrow + 32 + quad * 8);
    }
    floatx4 acc[2][4] = {};

    const unsigned short* Kbase = Kb + (size_t)(b * kS) * kD + h * kDh;
    const unsigned short* VTb   = VT + (size_t)bh * kDh * kS;

    // staging: lane covers row r0 = lane>>3 within its wave's 8-row band,
    // logical 16B chunk j = (lane&7) ^ r0 (8-chunk XOR swizzle, row&7 == r0)
    const int r0 = lane >> 3;
    const int jc = ((lane & 7) ^ r0) * 8;   // element offset of logical chunk
    const unsigned short* Kg[4];
    const unsigned short* Vg[4];
    unsigned short* Kl[4];
    unsigned short* Vl[4];
#pragma unroll
    for (int seg = 0; seg < 4; seg++) {
        const int row = seg * 16 + w * 8 + r0;         // 0..63
        Kg[seg] = Kbase + (size_t)row * kD + jc;       // + k0*kD per chunk
        Vg[seg] = VTb + (size_t)row * kS + jc;         // + k0 per chunk
        Kl[seg] = Ks  + (seg * 16 + w * 8) * 64;       // wave-uniform
        Vl[seg] = VTs + (seg * 16 + w * 8) * 64;
    }

    unsigned short* P = Pt[w];
    const int sw_w = quad * 16;          // P write swizzle
    const int sw_r = (l16 >> 2) * 16;    // P read swizzle
    const int pk0 = (quad ^ (l16 & 7)) * 8;        // physical chunk for logical quad
    const int pk1 = ((4 + quad) ^ (l16 & 7)) * 8;  // physical chunk for logical 4+quad

    for (int k0 = 0; k0 < kS; k0 += 64) {
        __syncthreads();
#pragma unroll
        for (int seg = 0; seg < 4; seg++) {
            gload16(Kg[seg] + (size_t)k0 * kD, Kl[seg]);
            gload16(Vg[seg] + k0, Vl[seg]);
        }
        __syncthreads();

        // K B-frags: B[k=d][n=key], key row = c*16+l16, d chunks quad / 4+quad
        short8 bk[4][2];
#pragma unroll
        for (int c = 0; c < 4; c++) {
            const unsigned short* row = Ks + (c * 16 + l16) * 64;
            bk[c][0] = *(const short8*)(row + pk0);
            bk[c][1] = *(const short8*)(row + pk1);
        }
        // S tiles
        floatx4 sc[2][4];
#pragma unroll
        for (int s = 0; s < 2; s++)
#pragma unroll
            for (int c = 0; c < 4; c++) {
                floatx4 t = {0.f, 0.f, 0.f, 0.f};
                t = mfma16(aq[s][0], bk[c][0], t);
                sc[s][c] = mfma16(aq[s][1], bk[c][1], t);
            }
        // exp2 -> P (own wave region, no extra barrier)
#pragma unroll
        for (int s = 0; s < 2; s++)
#pragma unroll
            for (int c = 0; c < 4; c++)
#pragma unroll
                for (int r = 0; r < 4; r++)
                    P[(s * 16 + quad * 4 + r) * LDP + ((c * 16 + l16) ^ sw_w)] =
                        f2b(exp2f(sc[s][c][r]));

        // VT B-frags: B[k][n=d], d row = t*16+l16, k chunks quad / 4+quad
        short8 bv[4][2];
#pragma unroll
        for (int t = 0; t < 4; t++) {
            const unsigned short* row = VTs + (t * 16 + l16) * 64;
            bv[t][0] = *(const short8*)(row + pk0);
            bv[t][1] = *(const short8*)(row + pk1);
        }
        // PV
#pragma unroll
        for (int s = 0; s < 2; s++) {
            short8 ap0 = *(const short8*)(P + (s * 16 + l16) * LDP + ((quad * 8) ^ sw_r));
            short8 ap1 = *(const short8*)(P + (s * 16 + l16) * LDP + ((32 + quad * 8) ^ sw_r));
#pragma unroll
            for (int t = 0; t < 4; t++) {
                acc[s][t] = mfma16(ap0, bv[t][0], acc[s][t]);
                acc[s][t] = mfma16(ap1, bv[t][1], acc[s][t]);
            }
        }
    }

#pragma unroll
    for (int s = 0; s < 2; s++)
#pragma unroll
        for (int t = 0; t < 4; t++)
#pragma unroll
            for (int r = 0; r < 4; r++)
                Ctx[(size_t)(b * kS + qbase + s * 16 + quad * 4 + r) * kD + h * kDh + t * 16 + l16] =
                    f2b(acc[s][t][r]);
}

// ---------------------------------------------------------------------------
// K4: row LayerNorm
// ---------------------------------------------------------------------------
__global__ void ln_kernel(const float* __restrict__ R, const float* __restrict__ gamma,
                          const float* __restrict__ beta, float* __restrict__ out) {
    const int row = blockIdx.x;
    const int tid = threadIdx.x;
    const float4 v = ((const float4*)(R + (size_t)row * kD))[tid];
    float s  = v.x + v.y + v.z + v.w;
    float ss = v.x * v.x + v.y * v.y + v.z * v.z + v.w * v.w;
#pragma unroll
    for (int off = 32; off > 0; off >>= 1) {
        s  += __shfl_down(s, off, 64);
        ss += __shfl_down(ss, off, 64);
    }
    __shared__ float ws_s[4], ws_ss[4];
    __shared__ float mu_sh, inv_sh;
    const int lane = tid & 63, w = tid >> 6;
    if (lane == 0) { ws_s[w] = s; ws_ss[w] = ss; }
    __syncthreads();
    if (tid == 0) {
        float S1 = ws_s[0] + ws_s[1] + ws_s[2] + ws_s[3];
        float S2 = ws_ss[0] + ws_ss[1] + ws_ss[2] + ws_ss[3];
        float mu = S1 * (1.0f / kD);
        float var = S2 * (1.0f / kD) - mu * mu;
        mu_sh = mu;
        inv_sh = rsqrtf(var + 1e-5f);
    }
    __syncthreads();
    const float mu = mu_sh, inv = inv_sh;
    const float4 g  = ((const float4*)gamma)[tid];
    const float4 bb = ((const float4*)beta)[tid];
    float4 o;
    o.x = (v.x - mu) * inv * g.x + bb.x;
    o.y = (v.y - mu) * inv * g.y + bb.y;
    o.z = (v.z - mu) * inv * g.z + bb.z;
    o.w = (v.w - mu) * inv * g.w + bb.w;
    ((float4*)(out + (size_t)row * kD))[tid] = o;
}

// ---------------------------------------------------------------------------
// Workspace layout (64.25 MB peak, aliasing is stream-ordered-safe):
//   [0,   8MB)  Xb bf16; REUSED as psum (1MB fp32) after QKV GEMM consumes Xb
//   [8,  16MB)  Wb bf16 wq|wk|wv|wo
//   [16, 40MB)  QKV bf16 Q|K|V  (Q pre-scaled by 0.125*log2e)
//   [40, 48MB)  Ctx bf16
//   [48, 64MB)  VT bf16 [32][64][2048]; ALIASES R (written strictly later)
//   [64MB, +256KB) invl fp32
// ---------------------------------------------------------------------------
extern "C" void kernel_launch(void* const* d_in, const int* in_sizes, int n_in,
                              void* d_out, int out_size, void* d_ws, size_t ws_size,
                              hipStream_t stream) {
    const float* x     = (const float*)d_in[0];
    const float* wq    = (const float*)d_in[1];
    const float* wk    = (const float*)d_in[2];
    const float* wv    = (const float*)d_in[3];
    const float* wo    = (const float*)d_in[4];
    const float* gamma = (const float*)d_in[5];
    const float* beta  = (const float*)d_in[6];
    float* out = (float*)d_out;

    char* ws = (char*)d_ws;
    unsigned short* Xb  = (unsigned short*)(ws);
    float*          psum = (float*)(ws);               // reuses Xb region
    unsigned short* Wb  = (unsigned short*)(ws + (8u  << 20));
    unsigned short* QKV = (unsigned short*)(ws + (16u << 20));
    unsigned short* Qb  = QKV;
    unsigned short* Kb  = QKV + (size_t)kBS * kD;
    unsigned short* Vb  = QKV + (size_t)2 * kBS * kD;
    unsigned short* Ctx = (unsigned short*)(ws + (40u << 20));
    unsigned short* VT  = (unsigned short*)(ws + (48u << 20));
    float* R            = (float*)(ws + (48u << 20));  // aliases VT
    float* invl         = (float*)(ws + (64u << 20));

    convert_kernel<<<8192, 256, 0, stream>>>(x, wq, wk, wv, wo, Xb, Wb);

    gemm_nt<0><<<dim3(kD / 128, kBS / 128, 3), 256, 0, stream>>>(
        Xb, Wb, QKV, nullptr, kBS, kD, kD);

    stats_kernel<<<dim3(kS / 64, kB * kH, 4), 256, 0, stream>>>(Qb, Kb, psum);

    invl_kernel<<<(32 * kS) / 256, 256, 0, stream>>>(psum, invl);

    vt_kernel<<<dim3(kS / 64, kB * kH), 256, 0, stream>>>(Vb, invl, VT);

    ctx_kernel<<<dim3(kS / 64, kB * kH), 128, 0, stream>>>(Qb, Kb, VT, Ctx);

    gemm_nt<1><<<dim3(kD / 128, kBS / 128, 1), 256, 0, stream>>>(
        Ctx, Wb + (size_t)3 * kD * kD, R, x, kBS, kD, kD);

    ln_kernel<<<kBS, 256, 0, stream>>>(R, gamma, beta, out);
}

// Round 5
// 282.271 us; speedup vs baseline: 1.7840x; 1.2438x over previous
//
#include <hip/hip_runtime.h>
#include <hip/hip_bf16.h>

// Problem constants
constexpr int kB   = 2;
constexpr int kS   = 2048;
constexpr int kD   = 1024;
constexpr int kH   = 16;
constexpr int kDh  = 64;
constexpr int kBS  = kB * kS;          // 4096 rows

typedef __attribute__((ext_vector_type(8))) short short8;   // 8 bf16 = 4 VGPRs
typedef __attribute__((ext_vector_type(4))) float floatx4;  // MFMA acc

__device__ inline unsigned short f2b(float f) {
    __hip_bfloat16 h = __float2bfloat16(f);
    return *reinterpret_cast<unsigned short*>(&h);
}

__device__ inline floatx4 mfma16(short8 a, short8 b, floatx4 c) {
    return __builtin_amdgcn_mfma_f32_16x16x32_bf16(a, b, c, 0, 0, 0);
}

// async global->LDS, 16B per lane; LDS dest = wave-uniform base + lane*16
__device__ inline void gload16(const unsigned short* g, unsigned short* l) {
    __builtin_amdgcn_global_load_lds(
        (const __attribute__((address_space(1))) void*)g,
        (__attribute__((address_space(3))) void*)l, 16, 0, 0);
}

// ---------------------------------------------------------------------------
// K0: fp32 -> bf16 conversion of x (4M elems) and the 4 weights (4 x 1M elems)
// ---------------------------------------------------------------------------
__global__ void convert_kernel(const float* __restrict__ x,
                               const float* __restrict__ wq, const float* __restrict__ wk,
                               const float* __restrict__ wv, const float* __restrict__ wo,
                               unsigned short* __restrict__ xb, unsigned short* __restrict__ wb) {
    int gid = blockIdx.x * blockDim.x + threadIdx.x;
    long i4 = (long)gid * 4;
    const float* src;
    unsigned short* dst;
    long off;
    if (i4 < (long)kBS * kD) {
        src = x; dst = xb; off = i4;
    } else {
        long w = i4 - (long)kBS * kD;
        int sel = (int)(w >> 20);
        off = w & 1048575;
        src = (sel == 0) ? wq : (sel == 1) ? wk : (sel == 2) ? wv : wo;
        dst = wb + (long)sel * 1048576;
    }
    float4 v = *(const float4*)(src + off);
    ushort4 o;
    o.x = f2b(v.x); o.y = f2b(v.y); o.z = f2b(v.z); o.w = f2b(v.w);
    *(ushort4*)(dst + off) = o;
}

// ---------------------------------------------------------------------------
// K1: NT GEMM  C[M,N] = A[M,K] @ B[N,K]^T   (bf16 in, fp32 accum)
// m97-style staging: global_load_lds width=16, XOR-swizzled k-chunks.
// MODE 0: bf16 C; z==0 (Q) scaled by 0.125*log2(e) (attention scale folded,
//         exp2 domain). MODE 1: fp32 C + residual.
// ---------------------------------------------------------------------------
template <int MODE>
__launch_bounds__(256, 2)
__global__ void gemm_nt(const unsigned short* __restrict__ A,
                        const unsigned short* __restrict__ Bw,
                        void* __restrict__ Cout,
                        const float* __restrict__ resid,
                        int M, int N, int K) {
    __shared__ __align__(16) unsigned short As[128 * 32];
    __shared__ __align__(16) unsigned short Bs[128 * 32];

    const int z  = blockIdx.z;
    const unsigned short* Bp = Bw + (size_t)z * N * K;
    const int m0 = blockIdx.y * 128, n0 = blockIdx.x * 128;
    const int tid  = threadIdx.x;
    const int lane = tid & 63, wv = tid >> 6;
    const int wm = wv >> 1, wn = wv & 1;
    const int quad = lane >> 4, l16 = lane & 15;

    floatx4 acc[4][4] = {};

    const int c0 = wv * 64 + lane;          // 0..255   (rows 0..63)
    const int c1 = 256 + c0;                // 256..511 (rows 64..127)
    const int ar0 = c0 >> 2, aj0 = ((c0 & 3) ^ (ar0 & 3)) * 8;
    const int ar1 = c1 >> 2, aj1 = ((c1 & 3) ^ (ar1 & 3)) * 8;
    const unsigned short* Ag0 = A  + (size_t)(m0 + ar0) * K + aj0;
    const unsigned short* Ag1 = A  + (size_t)(m0 + ar1) * K + aj1;
    const unsigned short* Bg0 = Bp + (size_t)(n0 + ar0) * K + aj0;
    const unsigned short* Bg1 = Bp + (size_t)(n0 + ar1) * K + aj1;
    unsigned short* Asd0 = As + wv * 512;
    unsigned short* Asd1 = As + (4 + wv) * 512;
    unsigned short* Bsd0 = Bs + wv * 512;
    unsigned short* Bsd1 = Bs + (4 + wv) * 512;

    for (int k0 = 0; k0 < K; k0 += 32) {
        __syncthreads();
        gload16(Ag0 + k0, Asd0);
        gload16(Ag1 + k0, Asd1);
        gload16(Bg0 + k0, Bsd0);
        gload16(Bg1 + k0, Bsd1);
        __syncthreads();

        short8 af[4], bf[4];
#pragma unroll
        for (int i = 0; i < 4; i++) {
            const int R = wm * 64 + i * 16 + l16;
            af[i] = *(const short8*)(As + R * 32 + (quad ^ (l16 & 3)) * 8);
        }
#pragma unroll
        for (int j = 0; j < 4; j++) {
            const int R = wn * 64 + j * 16 + l16;
            bf[j] = *(const short8*)(Bs + R * 32 + (quad ^ (l16 & 3)) * 8);
        }
#pragma unroll
        for (int i = 0; i < 4; i++)
#pragma unroll
            for (int j = 0; j < 4; j++)
                acc[i][j] = mfma16(af[i], bf[j], acc[i][j]);
    }

#pragma unroll
    for (int i = 0; i < 4; i++)
#pragma unroll
        for (int j = 0; j < 4; j++) {
            const int row = m0 + wm * 64 + i * 16 + quad * 4;
            const int col = n0 + wn * 64 + j * 16 + l16;
#pragma unroll
            for (int r = 0; r < 4; r++) {
                float v = acc[i][j][r];
                if (MODE == 0) {
                    if (z == 0) v *= 0.18033688f;   // 0.125 * log2(e): exp2 domain
                    ((unsigned short*)Cout)[(size_t)z * M * N + (size_t)(row + r) * N + col] = f2b(v);
                } else {
                    size_t idx = (size_t)(row + r) * N + col;
                    ((float*)Cout)[idx] = v + resid[idx];
                }
            }
        }
}

// ---------------------------------------------------------------------------
// K2: column-softmax denominators, K-stationary. invl[bh,k] = 1/sum_q exp2(s).
// Block = 128 threads (2 waves x 32 keys); grid (32, 32). A-frags = K rows in
// registers (loaded once). Loop q in 64-chunks: stage Q-tile (64x64, 8KB) via
// global_load_lds w=16 (XOR chunk swizzle), 16 MFMAs/wave computing
// S'[key][q], exp2 + per-lane column accumulate. Final shuffle-reduce over
// l16, direct invl write (no psum pass).
// ---------------------------------------------------------------------------
__launch_bounds__(128, 3)
__global__ void stats_kernel(const unsigned short* __restrict__ Qb,
                             const unsigned short* __restrict__ Kb,
                             float* __restrict__ invl) {
    __shared__ __align__(16) unsigned short Qs[64 * 64];

    const int bh = blockIdx.y;
    const int b = bh >> 4, h = bh & 15;
    const int tid = threadIdx.x, lane = tid & 63, w = tid >> 6;   // w = 0..1
    const int quad = lane >> 4, l16 = lane & 15;
    const int keybase = blockIdx.x * 64 + w * 32;

    // A-frags: K rows (2 key-tiles x 2 dh-halves), held in regs
    short8 ak[2][2];
#pragma unroll
    for (int s = 0; s < 2; s++) {
        const unsigned short* Krow = Kb + (size_t)(b * kS + keybase + s * 16 + l16) * kD + h * kDh;
        ak[s][0] = *(const short8*)(Krow + quad * 8);
        ak[s][1] = *(const short8*)(Krow + 32 + quad * 8);
    }

    // staging: lane covers row r0 = lane>>3 within its wave's 8-row band,
    // logical 16B chunk j = (lane&7) ^ r0
    const int r0 = lane >> 3;
    const int jc = ((lane & 7) ^ r0) * 8;
    const unsigned short* Qg[4];
    unsigned short* Ql[4];
#pragma unroll
    for (int seg = 0; seg < 4; seg++) {
        const int row = seg * 16 + w * 8 + r0;              // 0..63
        Qg[seg] = Qb + (size_t)(b * kS + row) * kD + h * kDh + jc;   // + q0*kD per chunk
        Ql[seg] = Qs + (seg * 16 + w * 8) * 64;             // wave-uniform
    }

    const int pk0 = (quad ^ (l16 & 7)) * 8;
    const int pk1 = ((4 + quad) ^ (l16 & 7)) * 8;

    float lacc[2][4] = {};

    for (int q0 = 0; q0 < kS; q0 += 64) {
        __syncthreads();
#pragma unroll
        for (int seg = 0; seg < 4; seg++)
            gload16(Qg[seg] + (size_t)q0 * kD, Ql[seg]);
        __syncthreads();

#pragma unroll
        for (int c = 0; c < 4; c++) {
            const unsigned short* row = Qs + (c * 16 + l16) * 64;
            short8 bq0 = *(const short8*)(row + pk0);
            short8 bq1 = *(const short8*)(row + pk1);
#pragma unroll
            for (int s = 0; s < 2; s++) {
                floatx4 t = {0.f, 0.f, 0.f, 0.f};
                t = mfma16(ak[s][0], bq0, t);
                t = mfma16(ak[s][1], bq1, t);
#pragma unroll
                for (int r = 0; r < 4; r++)
                    lacc[s][r] += exp2f(t[r]);
            }
        }
    }

    // reduce across the 16 l16 lanes within each quad
#pragma unroll
    for (int off = 1; off <= 8; off <<= 1)
#pragma unroll
        for (int s = 0; s < 2; s++)
#pragma unroll
            for (int r = 0; r < 4; r++)
                lacc[s][r] += __shfl_xor(lacc[s][r], off, 64);

    if (l16 == 0) {
#pragma unroll
        for (int s = 0; s < 2; s++)
#pragma unroll
            for (int r = 0; r < 4; r++)
                invl[(size_t)bh * kS + keybase + s * 16 + quad * 4 + r] = 1.0f / lacc[s][r];
    }
}

// ---------------------------------------------------------------------------
// K2b: VT[bh][d][k] = V[b][k][h*64+d] * invl[bh][k]   (pre-scaled V^T)
// ---------------------------------------------------------------------------
__global__ void vt_kernel(const unsigned short* __restrict__ Vb,
                          const float* __restrict__ invl,
                          unsigned short* __restrict__ VT) {
    __shared__ unsigned short tile[64 * 65];
    const int bh = blockIdx.y, b = bh >> 4, h = bh & 15;
    const int k0 = blockIdx.x * 64;
    const int tid = threadIdx.x;
    const int kr = tid >> 2, dc = (tid & 3) * 16;

    const float iv = invl[(size_t)bh * kS + k0 + kr];
    const unsigned short* src = Vb + (size_t)(b * kS + k0 + kr) * kD + h * kDh + dc;
    uint4 v0 = *(const uint4*)(src);
    uint4 v1 = *(const uint4*)(src + 8);
    unsigned short vs[16];
    *(uint4*)(vs) = v0; *(uint4*)(vs + 8) = v1;
#pragma unroll
    for (int i = 0; i < 16; i++) {
        __hip_bfloat16 hv = *reinterpret_cast<__hip_bfloat16*>(&vs[i]);
        tile[kr * 65 + dc + i] = f2b(__bfloat162float(hv) * iv);
    }
    __syncthreads();
    const int d = tid >> 2, kc = (tid & 3) * 16;
    unsigned short os[16];
#pragma unroll
    for (int j = 0; j < 16; j++) os[j] = tile[(kc + j) * 65 + d];
    unsigned short* dst = VT + (size_t)bh * kDh * kS + (size_t)d * kS + k0 + kc;
    *(uint4*)(dst)     = *(uint4*)(os);
    *(uint4*)(dst + 8) = *(uint4*)(os + 8);
}

// ---------------------------------------------------------------------------
// K3: ctx = exp2(S) @ VT^T — m97-style block staging.
// Block = 128 threads (2 waves x 32 q); grid (32, 32) = 1024 blocks.
// Per 64-key chunk: stage K-tile (64x64) + VT-tile (64x64) into LDS via
// global_load_lds w=16 (8-chunk XOR swizzle), then per wave: 16 S-MFMA ->
// exp2 -> P (own LDS region, stride-72 swizzle) -> 16 PV-MFMA.
// ---------------------------------------------------------------------------
__launch_bounds__(128, 3)
__global__ void ctx_kernel(const unsigned short* __restrict__ Qb,
                           const unsigned short* __restrict__ Kb,
                           const unsigned short* __restrict__ VT,
                           unsigned short* __restrict__ Ctx) {
    constexpr int LDP = 72;
    __shared__ __align__(16) unsigned short Ks[64 * 64];
    __shared__ __align__(16) unsigned short VTs[64 * 64];
    __shared__ __align__(16) unsigned short Pt[2][32 * LDP];

    const int bh = blockIdx.y;
    const int b = bh >> 4, h = bh & 15;
    const int tid = threadIdx.x, lane = tid & 63, w = tid >> 6;   // w = 0..1
    const int quad = lane >> 4, l16 = lane & 15;
    const int qbase = blockIdx.x * 64 + w * 32;

    short8 aq[2][2];
#pragma unroll
    for (int s = 0; s < 2; s++) {
        const unsigned short* Qrow = Qb + (size_t)(b * kS + qbase + s * 16 + l16) * kD + h * kDh;
        aq[s][0] = *(const short8*)(Qrow + quad * 8);
        aq[s][1] = *(const short8*)(Qrow + 32 + quad * 8);
    }
    floatx4 acc[2][4] = {};

    const unsigned short* Kbase = Kb + (size_t)(b * kS) * kD + h * kDh;
    const unsigned short* VTb   = VT + (size_t)bh * kDh * kS;

    const int r0 = lane >> 3;
    const int jc = ((lane & 7) ^ r0) * 8;
    const unsigned short* Kg[4];
    const unsigned short* Vg[4];
    unsigned short* Kl[4];
    unsigned short* Vl[4];
#pragma unroll
    for (int seg = 0; seg < 4; seg++) {
        const int row = seg * 16 + w * 8 + r0;         // 0..63
        Kg[seg] = Kbase + (size_t)row * kD + jc;       // + k0*kD per chunk
        Vg[seg] = VTb + (size_t)row * kS + jc;         // + k0 per chunk
        Kl[seg] = Ks  + (seg * 16 + w * 8) * 64;       // wave-uniform
        Vl[seg] = VTs + (seg * 16 + w * 8) * 64;
    }

    unsigned short* P = Pt[w];
    const int sw_w = quad * 16;          // P write swizzle
    const int sw_r = (l16 >> 2) * 16;    // P read swizzle
    const int pk0 = (quad ^ (l16 & 7)) * 8;
    const int pk1 = ((4 + quad) ^ (l16 & 7)) * 8;

    for (int k0 = 0; k0 < kS; k0 += 64) {
        __syncthreads();
#pragma unroll
        for (int seg = 0; seg < 4; seg++) {
            gload16(Kg[seg] + (size_t)k0 * kD, Kl[seg]);
            gload16(Vg[seg] + k0, Vl[seg]);
        }
        __syncthreads();

        short8 bk[4][2];
#pragma unroll
        for (int c = 0; c < 4; c++) {
            const unsigned short* row = Ks + (c * 16 + l16) * 64;
            bk[c][0] = *(const short8*)(row + pk0);
            bk[c][1] = *(const short8*)(row + pk1);
        }
        floatx4 sc[2][4];
#pragma unroll
        for (int s = 0; s < 2; s++)
#pragma unroll
            for (int c = 0; c < 4; c++) {
                floatx4 t = {0.f, 0.f, 0.f, 0.f};
                t = mfma16(aq[s][0], bk[c][0], t);
                sc[s][c] = mfma16(aq[s][1], bk[c][1], t);
            }
#pragma unroll
        for (int s = 0; s < 2; s++)
#pragma unroll
            for (int c = 0; c < 4; c++)
#pragma unroll
                for (int r = 0; r < 4; r++)
                    P[(s * 16 + quad * 4 + r) * LDP + ((c * 16 + l16) ^ sw_w)] =
                        f2b(exp2f(sc[s][c][r]));

        short8 bv[4][2];
#pragma unroll
        for (int t = 0; t < 4; t++) {
            const unsigned short* row = VTs + (t * 16 + l16) * 64;
            bv[t][0] = *(const short8*)(row + pk0);
            bv[t][1] = *(const short8*)(row + pk1);
        }
#pragma unroll
        for (int s = 0; s < 2; s++) {
            short8 ap0 = *(const short8*)(P + (s * 16 + l16) * LDP + ((quad * 8) ^ sw_r));
            short8 ap1 = *(const short8*)(P + (s * 16 + l16) * LDP + ((32 + quad * 8) ^ sw_r));
#pragma unroll
            for (int t = 0; t < 4; t++) {
                acc[s][t] = mfma16(ap0, bv[t][0], acc[s][t]);
                acc[s][t] = mfma16(ap1, bv[t][1], acc[s][t]);
            }
        }
    }

#pragma unroll
    for (int s = 0; s < 2; s++)
#pragma unroll
        for (int t = 0; t < 4; t++)
#pragma unroll
            for (int r = 0; r < 4; r++)
                Ctx[(size_t)(b * kS + qbase + s * 16 + quad * 4 + r) * kD + h * kDh + t * 16 + l16] =
                    f2b(acc[s][t][r]);
}

// ---------------------------------------------------------------------------
// K4: row LayerNorm
// ---------------------------------------------------------------------------
__global__ void ln_kernel(const float* __restrict__ R, const float* __restrict__ gamma,
                          const float* __restrict__ beta, float* __restrict__ out) {
    const int row = blockIdx.x;
    const int tid = threadIdx.x;
    const float4 v = ((const float4*)(R + (size_t)row * kD))[tid];
    float s  = v.x + v.y + v.z + v.w;
    float ss = v.x * v.x + v.y * v.y + v.z * v.z + v.w * v.w;
#pragma unroll
    for (int off = 32; off > 0; off >>= 1) {
        s  += __shfl_down(s, off, 64);
        ss += __shfl_down(ss, off, 64);
    }
    __shared__ float ws_s[4], ws_ss[4];
    __shared__ float mu_sh, inv_sh;
    const int lane = tid & 63, w = tid >> 6;
    if (lane == 0) { ws_s[w] = s; ws_ss[w] = ss; }
    __syncthreads();
    if (tid == 0) {
        float S1 = ws_s[0] + ws_s[1] + ws_s[2] + ws_s[3];
        float S2 = ws_ss[0] + ws_ss[1] + ws_ss[2] + ws_ss[3];
        float mu = S1 * (1.0f / kD);
        float var = S2 * (1.0f / kD) - mu * mu;
        mu_sh = mu;
        inv_sh = rsqrtf(var + 1e-5f);
    }
    __syncthreads();
    const float mu = mu_sh, inv = inv_sh;
    const float4 g  = ((const float4*)gamma)[tid];
    const float4 bb = ((const float4*)beta)[tid];
    float4 o;
    o.x = (v.x - mu) * inv * g.x + bb.x;
    o.y = (v.y - mu) * inv * g.y + bb.y;
    o.z = (v.z - mu) * inv * g.z + bb.z;
    o.w = (v.w - mu) * inv * g.w + bb.w;
    ((float4*)(out + (size_t)row * kD))[tid] = o;
}

// ---------------------------------------------------------------------------
// Workspace layout (64.25 MB peak, aliasing is stream-ordered-safe):
//   [0,   8MB)  Xb bf16
//   [8,  16MB)  Wb bf16 wq|wk|wv|wo
//   [16, 40MB)  QKV bf16 Q|K|V  (Q pre-scaled by 0.125*log2e)
//   [40, 48MB)  Ctx bf16
//   [48, 64MB)  VT bf16 [32][64][2048]; ALIASES R (written strictly later)
//   [64MB, +256KB) invl fp32
// ---------------------------------------------------------------------------
extern "C" void kernel_launch(void* const* d_in, const int* in_sizes, int n_in,
                              void* d_out, int out_size, void* d_ws, size_t ws_size,
                              hipStream_t stream) {
    const float* x     = (const float*)d_in[0];
    const float* wq    = (const float*)d_in[1];
    const float* wk    = (const float*)d_in[2];
    const float* wv    = (const float*)d_in[3];
    const float* wo    = (const float*)d_in[4];
    const float* gamma = (const float*)d_in[5];
    const float* beta  = (const float*)d_in[6];
    float* out = (float*)d_out;

    char* ws = (char*)d_ws;
    unsigned short* Xb  = (unsigned short*)(ws);
    unsigned short* Wb  = (unsigned short*)(ws + (8u  << 20));
    unsigned short* QKV = (unsigned short*)(ws + (16u << 20));
    unsigned short* Qb  = QKV;
    unsigned short* Kb  = QKV + (size_t)kBS * kD;
    unsigned short* Vb  = QKV + (size_t)2 * kBS * kD;
    unsigned short* Ctx = (unsigned short*)(ws + (40u << 20));
    unsigned short* VT  = (unsigned short*)(ws + (48u << 20));
    float* R            = (float*)(ws + (48u << 20));  // aliases VT
    float* invl         = (float*)(ws + (64u << 20));

    convert_kernel<<<8192, 256, 0, stream>>>(x, wq, wk, wv, wo, Xb, Wb);

    gemm_nt<0><<<dim3(kD / 128, kBS / 128, 3), 256, 0, stream>>>(
        Xb, Wb, QKV, nullptr, kBS, kD, kD);

    stats_kernel<<<dim3(kS / 64, kB * kH), 128, 0, stream>>>(Qb, Kb, invl);

    vt_kernel<<<dim3(kS / 64, kB * kH), 256, 0, stream>>>(Vb, invl, VT);

    ctx_kernel<<<dim3(kS / 64, kB * kH), 128, 0, stream>>>(Qb, Kb, VT, Ctx);

    gemm_nt<1><<<dim3(kD / 128, kBS / 128, 1), 256, 0, stream>>>(
        Ctx, Wb + (size_t)3 * kD * kD, R, x, kBS, kD, kD);

    ln_kernel<<<kBS, 256, 0, stream>>>(R, gamma, beta, out);
}

// Round 6
// 276.752 us; speedup vs baseline: 1.8195x; 1.0199x over previous
//
#include <hip/hip_runtime.h>
#include <hip/hip_bf16.h>

// Problem constants
constexpr int kB   = 2;
constexpr int kS   = 2048;
constexpr int kD   = 1024;
constexpr int kH   = 16;
constexpr int kDh  = 64;
constexpr int kBS  = kB * kS;          // 4096 rows

typedef __attribute__((ext_vector_type(8))) short short8;   // 8 bf16 = 4 VGPRs
typedef __attribute__((ext_vector_type(4))) float floatx4;  // MFMA acc

__device__ inline unsigned short f2b(float f) {
    __hip_bfloat16 h = __float2bfloat16(f);
    return *reinterpret_cast<unsigned short*>(&h);
}

__device__ inline floatx4 mfma16(short8 a, short8 b, floatx4 c) {
    return __builtin_amdgcn_mfma_f32_16x16x32_bf16(a, b, c, 0, 0, 0);
}

// async global->LDS, 16B per lane; LDS dest = wave-uniform base + lane*16
__device__ inline void gload16(const unsigned short* g, unsigned short* l) {
    __builtin_amdgcn_global_load_lds(
        (const __attribute__((address_space(1))) void*)g,
        (__attribute__((address_space(3))) void*)l, 16, 0, 0);
}

// ---------------------------------------------------------------------------
// K0: fp32 -> bf16 conversion of x (4M elems) and the 4 weights (4 x 1M elems)
// ---------------------------------------------------------------------------
__global__ void convert_kernel(const float* __restrict__ x,
                               const float* __restrict__ wq, const float* __restrict__ wk,
                               const float* __restrict__ wv, const float* __restrict__ wo,
                               unsigned short* __restrict__ xb, unsigned short* __restrict__ wb) {
    int gid = blockIdx.x * blockDim.x + threadIdx.x;
    long i4 = (long)gid * 4;
    const float* src;
    unsigned short* dst;
    long off;
    if (i4 < (long)kBS * kD) {
        src = x; dst = xb; off = i4;
    } else {
        long w = i4 - (long)kBS * kD;
        int sel = (int)(w >> 20);
        off = w & 1048575;
        src = (sel == 0) ? wq : (sel == 1) ? wk : (sel == 2) ? wv : wo;
        dst = wb + (long)sel * 1048576;
    }
    float4 v = *(const float4*)(src + off);
    ushort4 o;
    o.x = f2b(v.x); o.y = f2b(v.y); o.z = f2b(v.z); o.w = f2b(v.w);
    *(ushort4*)(dst + off) = o;
}

// ---------------------------------------------------------------------------
// K1: NT GEMM  C[M,N] = A[M,K] @ B[N,K]^T   (bf16 in, fp32 accum)
// m97-style staging: global_load_lds width=16, XOR-swizzled k-chunks.
// MODE 0: bf16 C; z==0 (Q) scaled by 0.125*log2(e) (attention scale folded,
//         exp2 domain). MODE 1: fp32 C + residual.
// ---------------------------------------------------------------------------
template <int MODE>
__launch_bounds__(256, 2)
__global__ void gemm_nt(const unsigned short* __restrict__ A,
                        const unsigned short* __restrict__ Bw,
                        void* __restrict__ Cout,
                        const float* __restrict__ resid,
                        int M, int N, int K) {
    __shared__ __align__(16) unsigned short As[128 * 32];
    __shared__ __align__(16) unsigned short Bs[128 * 32];

    const int z  = blockIdx.z;
    const unsigned short* Bp = Bw + (size_t)z * N * K;
    const int m0 = blockIdx.y * 128, n0 = blockIdx.x * 128;
    const int tid  = threadIdx.x;
    const int lane = tid & 63, wv = tid >> 6;
    const int wm = wv >> 1, wn = wv & 1;
    const int quad = lane >> 4, l16 = lane & 15;

    floatx4 acc[4][4] = {};

    const int c0 = wv * 64 + lane;          // 0..255   (rows 0..63)
    const int c1 = 256 + c0;                // 256..511 (rows 64..127)
    const int ar0 = c0 >> 2, aj0 = ((c0 & 3) ^ (ar0 & 3)) * 8;
    const int ar1 = c1 >> 2, aj1 = ((c1 & 3) ^ (ar1 & 3)) * 8;
    const unsigned short* Ag0 = A  + (size_t)(m0 + ar0) * K + aj0;
    const unsigned short* Ag1 = A  + (size_t)(m0 + ar1) * K + aj1;
    const unsigned short* Bg0 = Bp + (size_t)(n0 + ar0) * K + aj0;
    const unsigned short* Bg1 = Bp + (size_t)(n0 + ar1) * K + aj1;
    unsigned short* Asd0 = As + wv * 512;
    unsigned short* Asd1 = As + (4 + wv) * 512;
    unsigned short* Bsd0 = Bs + wv * 512;
    unsigned short* Bsd1 = Bs + (4 + wv) * 512;

    for (int k0 = 0; k0 < K; k0 += 32) {
        __syncthreads();
        gload16(Ag0 + k0, Asd0);
        gload16(Ag1 + k0, Asd1);
        gload16(Bg0 + k0, Bsd0);
        gload16(Bg1 + k0, Bsd1);
        __syncthreads();

        short8 af[4], bf[4];
#pragma unroll
        for (int i = 0; i < 4; i++) {
            const int R = wm * 64 + i * 16 + l16;
            af[i] = *(const short8*)(As + R * 32 + (quad ^ (l16 & 3)) * 8);
        }
#pragma unroll
        for (int j = 0; j < 4; j++) {
            const int R = wn * 64 + j * 16 + l16;
            bf[j] = *(const short8*)(Bs + R * 32 + (quad ^ (l16 & 3)) * 8);
        }
#pragma unroll
        for (int i = 0; i < 4; i++)
#pragma unroll
            for (int j = 0; j < 4; j++)
                acc[i][j] = mfma16(af[i], bf[j], acc[i][j]);
    }

#pragma unroll
    for (int i = 0; i < 4; i++)
#pragma unroll
        for (int j = 0; j < 4; j++) {
            const int row = m0 + wm * 64 + i * 16 + quad * 4;
            const int col = n0 + wn * 64 + j * 16 + l16;
#pragma unroll
            for (int r = 0; r < 4; r++) {
                float v = acc[i][j][r];
                if (MODE == 0) {
                    if (z == 0) v *= 0.18033688f;   // 0.125 * log2(e): exp2 domain
                    ((unsigned short*)Cout)[(size_t)z * M * N + (size_t)(row + r) * N + col] = f2b(v);
                } else {
                    size_t idx = (size_t)(row + r) * N + col;
                    ((float*)Cout)[idx] = v + resid[idx];
                }
            }
        }
}

// ---------------------------------------------------------------------------
// K2: column-softmax denominators, K-stationary. invl[bh,k] = 1/sum_q exp2(s).
// 1-D grid of 1024, XCD-swizzled decode: bh = (id&7) + 8*((id>>3)&3) so each
// XCD (id%8 round-robin) touches only 4 bh -> K/Q working set fits its L2.
// Block = 128 threads (2 waves x 32 keys). A-frags = K rows in registers.
// Loop q in 64-chunks: stage Q-tile via global_load_lds w=16 (XOR swizzle),
// 16 MFMAs/wave, exp2 + per-lane column accumulate, shuffle-reduce, invl.
// ---------------------------------------------------------------------------
__launch_bounds__(128, 3)
__global__ void stats_kernel(const unsigned short* __restrict__ Qb,
                             const unsigned short* __restrict__ Kb,
                             float* __restrict__ invl) {
    __shared__ __align__(16) unsigned short Qs[64 * 64];

    const int id = blockIdx.x;                       // 0..1023
    const int bh = (id & 7) + 8 * ((id >> 3) & 3);   // XCD-grouped
    const int keyblk = id >> 5;                      // 0..31
    const int b = bh >> 4, h = bh & 15;
    const int tid = threadIdx.x, lane = tid & 63, w = tid >> 6;   // w = 0..1
    const int quad = lane >> 4, l16 = lane & 15;
    const int keybase = keyblk * 64 + w * 32;

    // A-frags: K rows (2 key-tiles x 2 dh-halves), held in regs
    short8 ak[2][2];
#pragma unroll
    for (int s = 0; s < 2; s++) {
        const unsigned short* Krow = Kb + (size_t)(b * kS + keybase + s * 16 + l16) * kD + h * kDh;
        ak[s][0] = *(const short8*)(Krow + quad * 8);
        ak[s][1] = *(const short8*)(Krow + 32 + quad * 8);
    }

    // staging: lane covers row r0 = lane>>3 within its wave's 8-row band,
    // logical 16B chunk j = (lane&7) ^ r0
    const int r0 = lane >> 3;
    const int jc = ((lane & 7) ^ r0) * 8;
    const unsigned short* Qg[4];
    unsigned short* Ql[4];
#pragma unroll
    for (int seg = 0; seg < 4; seg++) {
        const int row = seg * 16 + w * 8 + r0;              // 0..63
        Qg[seg] = Qb + (size_t)(b * kS + row) * kD + h * kDh + jc;   // + q0*kD per chunk
        Ql[seg] = Qs + (seg * 16 + w * 8) * 64;             // wave-uniform
    }

    const int pk0 = (quad ^ (l16 & 7)) * 8;
    const int pk1 = ((4 + quad) ^ (l16 & 7)) * 8;

    float lacc[2][4] = {};

    for (int q0 = 0; q0 < kS; q0 += 64) {
        __syncthreads();
#pragma unroll
        for (int seg = 0; seg < 4; seg++)
            gload16(Qg[seg] + (size_t)q0 * kD, Ql[seg]);
        __syncthreads();

#pragma unroll
        for (int c = 0; c < 4; c++) {
            const unsigned short* row = Qs + (c * 16 + l16) * 64;
            short8 bq0 = *(const short8*)(row + pk0);
            short8 bq1 = *(const short8*)(row + pk1);
#pragma unroll
            for (int s = 0; s < 2; s++) {
                floatx4 t = {0.f, 0.f, 0.f, 0.f};
                t = mfma16(ak[s][0], bq0, t);
                t = mfma16(ak[s][1], bq1, t);
#pragma unroll
                for (int r = 0; r < 4; r++)
                    lacc[s][r] += exp2f(t[r]);
            }
        }
    }

    // reduce across the 16 l16 lanes within each quad
#pragma unroll
    for (int off = 1; off <= 8; off <<= 1)
#pragma unroll
        for (int s = 0; s < 2; s++)
#pragma unroll
            for (int r = 0; r < 4; r++)
                lacc[s][r] += __shfl_xor(lacc[s][r], off, 64);

    if (l16 == 0) {
#pragma unroll
        for (int s = 0; s < 2; s++)
#pragma unroll
            for (int r = 0; r < 4; r++)
                invl[(size_t)bh * kS + keybase + s * 16 + quad * 4 + r] = 1.0f / lacc[s][r];
    }
}

// ---------------------------------------------------------------------------
// K2b: VT[bh][d][k] = V[b][k][h*64+d] * invl[bh][k]   (pre-scaled V^T)
// ---------------------------------------------------------------------------
__global__ void vt_kernel(const unsigned short* __restrict__ Vb,
                          const float* __restrict__ invl,
                          unsigned short* __restrict__ VT) {
    __shared__ unsigned short tile[64 * 65];
    const int bh = blockIdx.y, b = bh >> 4, h = bh & 15;
    const int k0 = blockIdx.x * 64;
    const int tid = threadIdx.x;
    const int kr = tid >> 2, dc = (tid & 3) * 16;

    const float iv = invl[(size_t)bh * kS + k0 + kr];
    const unsigned short* src = Vb + (size_t)(b * kS + k0 + kr) * kD + h * kDh + dc;
    uint4 v0 = *(const uint4*)(src);
    uint4 v1 = *(const uint4*)(src + 8);
    unsigned short vs[16];
    *(uint4*)(vs) = v0; *(uint4*)(vs + 8) = v1;
#pragma unroll
    for (int i = 0; i < 16; i++) {
        __hip_bfloat16 hv = *reinterpret_cast<__hip_bfloat16*>(&vs[i]);
        tile[kr * 65 + dc + i] = f2b(__bfloat162float(hv) * iv);
    }
    __syncthreads();
    const int d = tid >> 2, kc = (tid & 3) * 16;
    unsigned short os[16];
#pragma unroll
    for (int j = 0; j < 16; j++) os[j] = tile[(kc + j) * 65 + d];
    unsigned short* dst = VT + (size_t)bh * kDh * kS + (size_t)d * kS + k0 + kc;
    *(uint4*)(dst)     = *(uint4*)(os);
    *(uint4*)(dst + 8) = *(uint4*)(os + 8);
}

// ---------------------------------------------------------------------------
// K3: ctx = exp2(S) @ VT^T — m97-style block staging.
// 1-D grid of 1024, XCD-swizzled decode: bh = (id&7) + 8*((id>>3)&3) so each
// XCD's L2 holds only 4 bh's K+VT (2 MB < 4 MB L2) -> kills the 3x HBM
// over-fetch from cross-XCD duplication.
// Block = 128 threads (2 waves x 32 q). Per 64-key chunk: stage K-tile +
// VT-tile into LDS via global_load_lds w=16 (8-chunk XOR swizzle), then per
// wave: 16 S-MFMA -> exp2 -> P (own LDS region, stride-72) -> 16 PV-MFMA.
// ---------------------------------------------------------------------------
__launch_bounds__(128, 3)
__global__ void ctx_kernel(const unsigned short* __restrict__ Qb,
                           const unsigned short* __restrict__ Kb,
                           const unsigned short* __restrict__ VT,
                           unsigned short* __restrict__ Ctx) {
    constexpr int LDP = 72;
    __shared__ __align__(16) unsigned short Ks[64 * 64];
    __shared__ __align__(16) unsigned short VTs[64 * 64];
    __shared__ __align__(16) unsigned short Pt[2][32 * LDP];

    const int id = blockIdx.x;                       // 0..1023
    const int bh = (id & 7) + 8 * ((id >> 3) & 3);   // XCD-grouped
    const int qblk = id >> 5;                        // 0..31
    const int b = bh >> 4, h = bh & 15;
    const int tid = threadIdx.x, lane = tid & 63, w = tid >> 6;   // w = 0..1
    const int quad = lane >> 4, l16 = lane & 15;
    const int qbase = qblk * 64 + w * 32;

    short8 aq[2][2];
#pragma unroll
    for (int s = 0; s < 2; s++) {
        const unsigned short* Qrow = Qb + (size_t)(b * kS + qbase + s * 16 + l16) * kD + h * kDh;
        aq[s][0] = *(const short8*)(Qrow + quad * 8);
        aq[s][1] = *(const short8*)(Qrow + 32 + quad * 8);
    }
    floatx4 acc[2][4] = {};

    const unsigned short* Kbase = Kb + (size_t)(b * kS) * kD + h * kDh;
    const unsigned short* VTb   = VT + (size_t)bh * kDh * kS;

    const int r0 = lane >> 3;
    const int jc = ((lane & 7) ^ r0) * 8;
    const unsigned short* Kg[4];
    const unsigned short* Vg[4];
    unsigned short* Kl[4];
    unsigned short* Vl[4];
#pragma unroll
    for (int seg = 0; seg < 4; seg++) {
        const int row = seg * 16 + w * 8 + r0;         // 0..63
        Kg[seg] = Kbase + (size_t)row * kD + jc;       // + k0*kD per chunk
        Vg[seg] = VTb + (size_t)row * kS + jc;         // + k0 per chunk
        Kl[seg] = Ks  + (seg * 16 + w * 8) * 64;       // wave-uniform
        Vl[seg] = VTs + (seg * 16 + w * 8) * 64;
    }

    unsigned short* P = Pt[w];
    const int sw_w = quad * 16;          // P write swizzle
    const int sw_r = (l16 >> 2) * 16;    // P read swizzle
    const int pk0 = (quad ^ (l16 & 7)) * 8;
    const int pk1 = ((4 + quad) ^ (l16 & 7)) * 8;

    for (int k0 = 0; k0 < kS; k0 += 64) {
        __syncthreads();
#pragma unroll
        for (int seg = 0; seg < 4; seg++) {
            gload16(Kg[seg] + (size_t)k0 * kD, Kl[seg]);
            gload16(Vg[seg] + k0, Vl[seg]);
        }
        __syncthreads();

        short8 bk[4][2];
#pragma unroll
        for (int c = 0; c < 4; c++) {
            const unsigned short* row = Ks + (c * 16 + l16) * 64;
            bk[c][0] = *(const short8*)(row + pk0);
            bk[c][1] = *(const short8*)(row + pk1);
        }
        floatx4 sc[2][4];
#pragma unroll
        for (int s = 0; s < 2; s++)
#pragma unroll
            for (int c = 0; c < 4; c++) {
                floatx4 t = {0.f, 0.f, 0.f, 0.f};
                t = mfma16(aq[s][0], bk[c][0], t);
                sc[s][c] = mfma16(aq[s][1], bk[c][1], t);
            }
#pragma unroll
        for (int s = 0; s < 2; s++)
#pragma unroll
            for (int c = 0; c < 4; c++)
#pragma unroll
                for (int r = 0; r < 4; r++)
                    P[(s * 16 + quad * 4 + r) * LDP + ((c * 16 + l16) ^ sw_w)] =
                        f2b(exp2f(sc[s][c][r]));

        short8 bv[4][2];
#pragma unroll
        for (int t = 0; t < 4; t++) {
            const unsigned short* row = VTs + (t * 16 + l16) * 64;
            bv[t][0] = *(const short8*)(row + pk0);
            bv[t][1] = *(const short8*)(row + pk1);
        }
#pragma unroll
        for (int s = 0; s < 2; s++) {
            short8 ap0 = *(const short8*)(P + (s * 16 + l16) * LDP + ((quad * 8) ^ sw_r));
            short8 ap1 = *(const short8*)(P + (s * 16 + l16) * LDP + ((32 + quad * 8) ^ sw_r));
#pragma unroll
            for (int t = 0; t < 4; t++) {
                acc[s][t] = mfma16(ap0, bv[t][0], acc[s][t]);
                acc[s][t] = mfma16(ap1, bv[t][1], acc[s][t]);
            }
        }
    }

#pragma unroll
    for (int s = 0; s < 2; s++)
#pragma unroll
        for (int t = 0; t < 4; t++)
#pragma unroll
            for (int r = 0; r < 4; r++)
                Ctx[(size_t)(b * kS + qbase + s * 16 + quad * 4 + r) * kD + h * kDh + t * 16 + l16] =
                    f2b(acc[s][t][r]);
}

// ---------------------------------------------------------------------------
// K4: row LayerNorm
// ---------------------------------------------------------------------------
__global__ void ln_kernel(const float* __restrict__ R, const float* __restrict__ gamma,
                          const float* __restrict__ beta, float* __restrict__ out) {
    const int row = blockIdx.x;
    const int tid = threadIdx.x;
    const float4 v = ((const float4*)(R + (size_t)row * kD))[tid];
    float s  = v.x + v.y + v.z + v.w;
    float ss = v.x * v.x + v.y * v.y + v.z * v.z + v.w * v.w;
#pragma unroll
    for (int off = 32; off > 0; off >>= 1) {
        s  += __shfl_down(s, off, 64);
        ss += __shfl_down(ss, off, 64);
    }
    __shared__ float ws_s[4], ws_ss[4];
    __shared__ float mu_sh, inv_sh;
    const int lane = tid & 63, w = tid >> 6;
    if (lane == 0) { ws_s[w] = s; ws_ss[w] = ss; }
    __syncthreads();
    if (tid == 0) {
        float S1 = ws_s[0] + ws_s[1] + ws_s[2] + ws_s[3];
        float S2 = ws_ss[0] + ws_ss[1] + ws_ss[2] + ws_ss[3];
        float mu = S1 * (1.0f / kD);
        float var = S2 * (1.0f / kD) - mu * mu;
        mu_sh = mu;
        inv_sh = rsqrtf(var + 1e-5f);
    }
    __syncthreads();
    const float mu = mu_sh, inv = inv_sh;
    const float4 g  = ((const float4*)gamma)[tid];
    const float4 bb = ((const float4*)beta)[tid];
    float4 o;
    o.x = (v.x - mu) * inv * g.x + bb.x;
    o.y = (v.y - mu) * inv * g.y + bb.y;
    o.z = (v.z - mu) * inv * g.z + bb.z;
    o.w = (v.w - mu) * inv * g.w + bb.w;
    ((float4*)(out + (size_t)row * kD))[tid] = o;
}

// ---------------------------------------------------------------------------
// Workspace layout (64.25 MB peak, aliasing is stream-ordered-safe):
//   [0,   8MB)  Xb bf16
//   [8,  16MB)  Wb bf16 wq|wk|wv|wo
//   [16, 40MB)  QKV bf16 Q|K|V  (Q pre-scaled by 0.125*log2e)
//   [40, 48MB)  Ctx bf16
//   [48, 64MB)  VT bf16 [32][64][2048]; ALIASES R (written strictly later)
//   [64MB, +256KB) invl fp32
// ---------------------------------------------------------------------------
extern "C" void kernel_launch(void* const* d_in, const int* in_sizes, int n_in,
                              void* d_out, int out_size, void* d_ws, size_t ws_size,
                              hipStream_t stream) {
    const float* x     = (const float*)d_in[0];
    const float* wq    = (const float*)d_in[1];
    const float* wk    = (const float*)d_in[2];
    const float* wv    = (const float*)d_in[3];
    const float* wo    = (const float*)d_in[4];
    const float* gamma = (const float*)d_in[5];
    const float* beta  = (const float*)d_in[6];
    float* out = (float*)d_out;

    char* ws = (char*)d_ws;
    unsigned short* Xb  = (unsigned short*)(ws);
    unsigned short* Wb  = (unsigned short*)(ws + (8u  << 20));
    unsigned short* QKV = (unsigned short*)(ws + (16u << 20));
    unsigned short* Qb  = QKV;
    unsigned short* Kb  = QKV + (size_t)kBS * kD;
    unsigned short* Vb  = QKV + (size_t)2 * kBS * kD;
    unsigned short* Ctx = (unsigned short*)(ws + (40u << 20));
    unsigned short* VT  = (unsigned short*)(ws + (48u << 20));
    float* R            = (float*)(ws + (48u << 20));  // aliases VT
    float* invl         = (float*)(ws + (64u << 20));

    convert_kernel<<<8192, 256, 0, stream>>>(x, wq, wk, wv, wo, Xb, Wb);

    gemm_nt<0><<<dim3(kD / 128, kBS / 128, 3), 256, 0, stream>>>(
        Xb, Wb, QKV, nullptr, kBS, kD, kD);

    stats_kernel<<<1024, 128, 0, stream>>>(Qb, Kb, invl);

    vt_kernel<<<dim3(kS / 64, kB * kH), 256, 0, stream>>>(Vb, invl, VT);

    ctx_kernel<<<1024, 128, 0, stream>>>(Qb, Kb, VT, Ctx);

    gemm_nt<1><<<dim3(kD / 128, kBS / 128, 1), 256, 0, stream>>>(
        Ctx, Wb + (size_t)3 * kD * kD, R, x, kBS, kD, kD);

    ln_kernel<<<kBS, 256, 0, stream>>>(R, gamma, beta, out);
}

// Round 7
// 273.583 us; speedup vs baseline: 1.8406x; 1.0116x over previous
//
#include <hip/hip_runtime.h>
#include <hip/hip_bf16.h>

// Problem constants
constexpr int kB   = 2;
constexpr int kS   = 2048;
constexpr int kD   = 1024;
constexpr int kH   = 16;
constexpr int kDh  = 64;
constexpr int kBS  = kB * kS;          // 4096 rows

typedef __attribute__((ext_vector_type(8))) short short8;   // 8 bf16 = 4 VGPRs
typedef __attribute__((ext_vector_type(4))) float floatx4;  // MFMA acc

__device__ inline unsigned short f2b(float f) {
    __hip_bfloat16 h = __float2bfloat16(f);
    return *reinterpret_cast<unsigned short*>(&h);
}

__device__ inline floatx4 mfma16(short8 a, short8 b, floatx4 c) {
    return __builtin_amdgcn_mfma_f32_16x16x32_bf16(a, b, c, 0, 0, 0);
}

// async global->LDS, 16B per lane; LDS dest = wave-uniform base + lane*16
__device__ inline void gload16(const unsigned short* g, unsigned short* l) {
    __builtin_amdgcn_global_load_lds(
        (const __attribute__((address_space(1))) void*)g,
        (__attribute__((address_space(3))) void*)l, 16, 0, 0);
}

// ---------------------------------------------------------------------------
// K0: fp32 -> bf16 conversion of x (4M elems) and the 4 weights (4 x 1M elems)
// ---------------------------------------------------------------------------
__global__ void convert_kernel(const float* __restrict__ x,
                               const float* __restrict__ wq, const float* __restrict__ wk,
                               const float* __restrict__ wv, const float* __restrict__ wo,
                               unsigned short* __restrict__ xb, unsigned short* __restrict__ wb) {
    int gid = blockIdx.x * blockDim.x + threadIdx.x;
    long i4 = (long)gid * 4;
    const float* src;
    unsigned short* dst;
    long off;
    if (i4 < (long)kBS * kD) {
        src = x; dst = xb; off = i4;
    } else {
        long w = i4 - (long)kBS * kD;
        int sel = (int)(w >> 20);
        off = w & 1048575;
        src = (sel == 0) ? wq : (sel == 1) ? wk : (sel == 2) ? wv : wo;
        dst = wb + (long)sel * 1048576;
    }
    float4 v = *(const float4*)(src + off);
    ushort4 o;
    o.x = f2b(v.x); o.y = f2b(v.y); o.z = f2b(v.z); o.w = f2b(v.w);
    *(ushort4*)(dst + off) = o;
}

// ---------------------------------------------------------------------------
// K1: NT GEMM  C[M,N] = A[M,K] @ B[N,K]^T   (bf16 in, fp32 accum)
// m97-style staging: global_load_lds width=16, XOR-swizzled k-chunks.
// MODE 0: bf16 C; z==0 (Q) scaled by 0.125*log2(e) (attention scale folded,
//         exp2 domain). MODE 1: fp32 C + residual.
// ---------------------------------------------------------------------------
template <int MODE>
__launch_bounds__(256, 2)
__global__ void gemm_nt(const unsigned short* __restrict__ A,
                        const unsigned short* __restrict__ Bw,
                        void* __restrict__ Cout,
                        const float* __restrict__ resid,
                        int M, int N, int K) {
    __shared__ __align__(16) unsigned short As[128 * 32];
    __shared__ __align__(16) unsigned short Bs[128 * 32];

    const int z  = blockIdx.z;
    const unsigned short* Bp = Bw + (size_t)z * N * K;
    const int m0 = blockIdx.y * 128, n0 = blockIdx.x * 128;
    const int tid  = threadIdx.x;
    const int lane = tid & 63, wv = tid >> 6;
    const int wm = wv >> 1, wn = wv & 1;
    const int quad = lane >> 4, l16 = lane & 15;

    floatx4 acc[4][4] = {};

    const int c0 = wv * 64 + lane;          // 0..255   (rows 0..63)
    const int c1 = 256 + c0;                // 256..511 (rows 64..127)
    const int ar0 = c0 >> 2, aj0 = ((c0 & 3) ^ (ar0 & 3)) * 8;
    const int ar1 = c1 >> 2, aj1 = ((c1 & 3) ^ (ar1 & 3)) * 8;
    const unsigned short* Ag0 = A  + (size_t)(m0 + ar0) * K + aj0;
    const unsigned short* Ag1 = A  + (size_t)(m0 + ar1) * K + aj1;
    const unsigned short* Bg0 = Bp + (size_t)(n0 + ar0) * K + aj0;
    const unsigned short* Bg1 = Bp + (size_t)(n0 + ar1) * K + aj1;
    unsigned short* Asd0 = As + wv * 512;
    unsigned short* Asd1 = As + (4 + wv) * 512;
    unsigned short* Bsd0 = Bs + wv * 512;
    unsigned short* Bsd1 = Bs + (4 + wv) * 512;

    for (int k0 = 0; k0 < K; k0 += 32) {
        __syncthreads();
        gload16(Ag0 + k0, Asd0);
        gload16(Ag1 + k0, Asd1);
        gload16(Bg0 + k0, Bsd0);
        gload16(Bg1 + k0, Bsd1);
        __syncthreads();

        short8 af[4], bf[4];
#pragma unroll
        for (int i = 0; i < 4; i++) {
            const int R = wm * 64 + i * 16 + l16;
            af[i] = *(const short8*)(As + R * 32 + (quad ^ (l16 & 3)) * 8);
        }
#pragma unroll
        for (int j = 0; j < 4; j++) {
            const int R = wn * 64 + j * 16 + l16;
            bf[j] = *(const short8*)(Bs + R * 32 + (quad ^ (l16 & 3)) * 8);
        }
#pragma unroll
        for (int i = 0; i < 4; i++)
#pragma unroll
            for (int j = 0; j < 4; j++)
                acc[i][j] = mfma16(af[i], bf[j], acc[i][j]);
    }

#pragma unroll
    for (int i = 0; i < 4; i++)
#pragma unroll
        for (int j = 0; j < 4; j++) {
            const int row = m0 + wm * 64 + i * 16 + quad * 4;
            const int col = n0 + wn * 64 + j * 16 + l16;
#pragma unroll
            for (int r = 0; r < 4; r++) {
                float v = acc[i][j][r];
                if (MODE == 0) {
                    if (z == 0) v *= 0.18033688f;   // 0.125 * log2(e): exp2 domain
                    ((unsigned short*)Cout)[(size_t)z * M * N + (size_t)(row + r) * N + col] = f2b(v);
                } else {
                    size_t idx = (size_t)(row + r) * N + col;
                    ((float*)Cout)[idx] = v + resid[idx];
                }
            }
        }
}

// ---------------------------------------------------------------------------
// K2: FUSED column-softmax denominators + scaled V^T production.
// Phase 1 (stats): invl[k] = 1/sum_q exp2(s[q,k]) for this block's 64 keys
//   (K-stationary, Q staged via global_load_lds, XCD-swizzled bh decode).
// Phase 2 (vt): VT[bh][d][k] = V[b][k][h*64+d] * invl[k] for the same 64
//   keys, invl broadcast through LDS — no global invl round-trip.
// ---------------------------------------------------------------------------
__launch_bounds__(128, 3)
__global__ void stats_vt_kernel(const unsigned short* __restrict__ Qb,
                                const unsigned short* __restrict__ Kb,
                                const unsigned short* __restrict__ Vb,
                                unsigned short* __restrict__ VT) {
    __shared__ __align__(16) unsigned short Qs[64 * 68];  // staging (stride 64) / transpose tile (stride 65)
    __shared__ float s_inv[64];

    const int id = blockIdx.x;                       // 0..1023
    const int bh = (id & 7) + 8 * ((id >> 3) & 3);   // XCD-grouped
    const int keyblk = id >> 5;                      // 0..31
    const int b = bh >> 4, h = bh & 15;
    const int tid = threadIdx.x, lane = tid & 63, w = tid >> 6;   // w = 0..1
    const int quad = lane >> 4, l16 = lane & 15;
    const int keybase = keyblk * 64 + w * 32;

    // A-frags: K rows (2 key-tiles x 2 dh-halves), held in regs
    short8 ak[2][2];
#pragma unroll
    for (int s = 0; s < 2; s++) {
        const unsigned short* Krow = Kb + (size_t)(b * kS + keybase + s * 16 + l16) * kD + h * kDh;
        ak[s][0] = *(const short8*)(Krow + quad * 8);
        ak[s][1] = *(const short8*)(Krow + 32 + quad * 8);
    }

    // staging: lane covers row r0 = lane>>3 within its wave's 8-row band,
    // logical 16B chunk j = (lane&7) ^ r0
    const int r0 = lane >> 3;
    const int jc = ((lane & 7) ^ r0) * 8;
    const unsigned short* Qg[4];
    unsigned short* Ql[4];
#pragma unroll
    for (int seg = 0; seg < 4; seg++) {
        const int row = seg * 16 + w * 8 + r0;              // 0..63
        Qg[seg] = Qb + (size_t)(b * kS + row) * kD + h * kDh + jc;   // + q0*kD per chunk
        Ql[seg] = Qs + (seg * 16 + w * 8) * 64;             // wave-uniform
    }

    const int pk0 = (quad ^ (l16 & 7)) * 8;
    const int pk1 = ((4 + quad) ^ (l16 & 7)) * 8;

    float lacc[2][4] = {};

    for (int q0 = 0; q0 < kS; q0 += 64) {
        __syncthreads();
#pragma unroll
        for (int seg = 0; seg < 4; seg++)
            gload16(Qg[seg] + (size_t)q0 * kD, Ql[seg]);
        __syncthreads();

#pragma unroll
        for (int c = 0; c < 4; c++) {
            const unsigned short* row = Qs + (c * 16 + l16) * 64;
            short8 bq0 = *(const short8*)(row + pk0);
            short8 bq1 = *(const short8*)(row + pk1);
#pragma unroll
            for (int s = 0; s < 2; s++) {
                floatx4 t = {0.f, 0.f, 0.f, 0.f};
                t = mfma16(ak[s][0], bq0, t);
                t = mfma16(ak[s][1], bq1, t);
#pragma unroll
                for (int r = 0; r < 4; r++)
                    lacc[s][r] += exp2f(t[r]);
            }
        }
    }

    // reduce across the 16 l16 lanes within each quad
#pragma unroll
    for (int off = 1; off <= 8; off <<= 1)
#pragma unroll
        for (int s = 0; s < 2; s++)
#pragma unroll
            for (int r = 0; r < 4; r++)
                lacc[s][r] += __shfl_xor(lacc[s][r], off, 64);

    __syncthreads();   // Qs reads done before tile reuse; also orders s_inv
    if (l16 == 0) {
#pragma unroll
        for (int s = 0; s < 2; s++)
#pragma unroll
            for (int r = 0; r < 4; r++)
                s_inv[w * 32 + s * 16 + quad * 4 + r] = 1.0f / lacc[s][r];
    }
    __syncthreads();

    // Phase 2: scaled V^T for this block's 64 keys. 128 threads:
    // load: thread (kr = tid>>1, dc = (tid&1)*32) covers 32 d of one V row.
    unsigned short* tile = Qs;   // reuse, stride 65
    {
        const int kr = tid >> 1, dc = (tid & 1) * 32;
        const float iv = s_inv[kr];
        const unsigned short* src = Vb + (size_t)(b * kS + keyblk * 64 + kr) * kD + h * kDh + dc;
        unsigned short vs[32];
        *(uint4*)(vs)      = *(const uint4*)(src);
        *(uint4*)(vs + 8)  = *(const uint4*)(src + 8);
        *(uint4*)(vs + 16) = *(const uint4*)(src + 16);
        *(uint4*)(vs + 24) = *(const uint4*)(src + 24);
#pragma unroll
        for (int i = 0; i < 32; i++) {
            __hip_bfloat16 hv = *reinterpret_cast<__hip_bfloat16*>(&vs[i]);
            tile[kr * 65 + dc + i] = f2b(__bfloat162float(hv) * iv);
        }
    }
    __syncthreads();
    {
        const int d = tid >> 1, kc = (tid & 1) * 32;
        unsigned short os[32];
#pragma unroll
        for (int j = 0; j < 32; j++) os[j] = tile[(kc + j) * 65 + d];
        unsigned short* dst = VT + (size_t)bh * kDh * kS + (size_t)d * kS + keyblk * 64 + kc;
        *(uint4*)(dst)      = *(uint4*)(os);
        *(uint4*)(dst + 8)  = *(uint4*)(os + 8);
        *(uint4*)(dst + 16) = *(uint4*)(os + 16);
        *(uint4*)(dst + 24) = *(uint4*)(os + 24);
    }
}

// ---------------------------------------------------------------------------
// K3: ctx = exp2(S) @ VT^T — m97-style block staging, XCD-swizzled.
// Round-7: (a) P stores are truncating bf16 (high-half of fp32 — zero-VALU
// convert, ds_write_b16_d16_hi pattern); (b) all P LDS addresses hoisted out
// of the k-loop so ds ops use immediate offsets (no per-access VALU).
// ---------------------------------------------------------------------------
__launch_bounds__(128, 3)
__global__ void ctx_kernel(const unsigned short* __restrict__ Qb,
                           const unsigned short* __restrict__ Kb,
                           const unsigned short* __restrict__ VT,
                           unsigned short* __restrict__ Ctx) {
    constexpr int LDP = 72;
    __shared__ __align__(16) unsigned short Ks[64 * 64];
    __shared__ __align__(16) unsigned short VTs[64 * 64];
    __shared__ __align__(16) unsigned short Pt[2][32 * LDP];

    const int id = blockIdx.x;                       // 0..1023
    const int bh = (id & 7) + 8 * ((id >> 3) & 3);   // XCD-grouped
    const int qblk = id >> 5;                        // 0..31
    const int b = bh >> 4, h = bh & 15;
    const int tid = threadIdx.x, lane = tid & 63, w = tid >> 6;   // w = 0..1
    const int quad = lane >> 4, l16 = lane & 15;
    const int qbase = qblk * 64 + w * 32;

    short8 aq[2][2];
#pragma unroll
    for (int s = 0; s < 2; s++) {
        const unsigned short* Qrow = Qb + (size_t)(b * kS + qbase + s * 16 + l16) * kD + h * kDh;
        aq[s][0] = *(const short8*)(Qrow + quad * 8);
        aq[s][1] = *(const short8*)(Qrow + 32 + quad * 8);
    }
    floatx4 acc[2][4] = {};

    const unsigned short* Kbase = Kb + (size_t)(b * kS) * kD + h * kDh;
    const unsigned short* VTb   = VT + (size_t)bh * kDh * kS;

    const int r0 = lane >> 3;
    const int jc = ((lane & 7) ^ r0) * 8;
    const unsigned short* Kg[4];
    const unsigned short* Vg[4];
    unsigned short* Kl[4];
    unsigned short* Vl[4];
#pragma unroll
    for (int seg = 0; seg < 4; seg++) {
        const int row = seg * 16 + w * 8 + r0;         // 0..63
        Kg[seg] = Kbase + (size_t)row * kD + jc;       // + k0*kD per chunk
        Vg[seg] = VTb + (size_t)row * kS + jc;         // + k0 per chunk
        Kl[seg] = Ks  + (seg * 16 + w * 8) * 64;       // wave-uniform
        Vl[seg] = VTs + (seg * 16 + w * 8) * 64;
    }

    unsigned short* P = Pt[w];
    // Hoisted P pointers. Write addr algebra: (s*16+quad*4+r)*LDP +
    // ((c*16+l16)^(quad*16)) = quad*4*LDP + (c^quad)*16 + l16 + (s*16+r)*LDP.
    unsigned short* pw[4];
#pragma unroll
    for (int c = 0; c < 4; c++)
        pw[c] = P + quad * 4 * LDP + (c ^ quad) * 16 + l16;
    // Read: P + (s*16+l16)*LDP + ((h2*32+quad*8)^((l16>>2)*16))
    const int sw_r = (l16 >> 2) * 16;
    const unsigned short* pr0 = P + l16 * LDP + ((quad * 8) ^ sw_r);
    const unsigned short* pr1 = P + l16 * LDP + ((32 + quad * 8) ^ sw_r);

    const int pk0 = (quad ^ (l16 & 7)) * 8;
    const int pk1 = ((4 + quad) ^ (l16 & 7)) * 8;

    for (int k0 = 0; k0 < kS; k0 += 64) {
        __syncthreads();
#pragma unroll
        for (int seg = 0; seg < 4; seg++) {
            gload16(Kg[seg] + (size_t)k0 * kD, Kl[seg]);
            gload16(Vg[seg] + k0, Vl[seg]);
        }
        __syncthreads();

        short8 bk[4][2];
#pragma unroll
        for (int c = 0; c < 4; c++) {
            const unsigned short* row = Ks + (c * 16 + l16) * 64;
            bk[c][0] = *(const short8*)(row + pk0);
            bk[c][1] = *(const short8*)(row + pk1);
        }
        floatx4 sc[2][4];
#pragma unroll
        for (int s = 0; s < 2; s++)
#pragma unroll
            for (int c = 0; c < 4; c++) {
                floatx4 t = {0.f, 0.f, 0.f, 0.f};
                t = mfma16(aq[s][0], bk[c][0], t);
                sc[s][c] = mfma16(aq[s][1], bk[c][1], t);
            }
        // exp2 -> P: truncating bf16 store (high half), immediate-offset ds ops
#pragma unroll
        for (int s = 0; s < 2; s++)
#pragma unroll
            for (int c = 0; c < 4; c++)
#pragma unroll
                for (int r = 0; r < 4; r++) {
                    union { float f; unsigned u; } cv;
                    cv.f = exp2f(sc[s][c][r]);
                    pw[c][(s * 16 + r) * LDP] = (unsigned short)(cv.u >> 16);
                }

        short8 bv[4][2];
#pragma unroll
        for (int t = 0; t < 4; t++) {
            const unsigned short* row = VTs + (t * 16 + l16) * 64;
            bv[t][0] = *(const short8*)(row + pk0);
            bv[t][1] = *(const short8*)(row + pk1);
        }
#pragma unroll
        for (int s = 0; s < 2; s++) {
            short8 ap0 = *(const short8*)(pr0 + s * 16 * LDP);
            short8 ap1 = *(const short8*)(pr1 + s * 16 * LDP);
#pragma unroll
            for (int t = 0; t < 4; t++) {
                acc[s][t] = mfma16(ap0, bv[t][0], acc[s][t]);
                acc[s][t] = mfma16(ap1, bv[t][1], acc[s][t]);
            }
        }
    }

#pragma unroll
    for (int s = 0; s < 2; s++)
#pragma unroll
        for (int t = 0; t < 4; t++)
#pragma unroll
            for (int r = 0; r < 4; r++)
                Ctx[(size_t)(b * kS + qbase + s * 16 + quad * 4 + r) * kD + h * kDh + t * 16 + l16] =
                    f2b(acc[s][t][r]);
}

// ---------------------------------------------------------------------------
// K4: row LayerNorm
// ---------------------------------------------------------------------------
__global__ void ln_kernel(const float* __restrict__ R, const float* __restrict__ gamma,
                          const float* __restrict__ beta, float* __restrict__ out) {
    const int row = blockIdx.x;
    const int tid = threadIdx.x;
    const float4 v = ((const float4*)(R + (size_t)row * kD))[tid];
    float s  = v.x + v.y + v.z + v.w;
    float ss = v.x * v.x + v.y * v.y + v.z * v.z + v.w * v.w;
#pragma unroll
    for (int off = 32; off > 0; off >>= 1) {
        s  += __shfl_down(s, off, 64);
        ss += __shfl_down(ss, off, 64);
    }
    __shared__ float ws_s[4], ws_ss[4];
    __shared__ float mu_sh, inv_sh;
    const int lane = tid & 63, w = tid >> 6;
    if (lane == 0) { ws_s[w] = s; ws_ss[w] = ss; }
    __syncthreads();
    if (tid == 0) {
        float S1 = ws_s[0] + ws_s[1] + ws_s[2] + ws_s[3];
        float S2 = ws_ss[0] + ws_ss[1] + ws_ss[2] + ws_ss[3];
        float mu = S1 * (1.0f / kD);
        float var = S2 * (1.0f / kD) - mu * mu;
        mu_sh = mu;
        inv_sh = rsqrtf(var + 1e-5f);
    }
    __syncthreads();
    const float mu = mu_sh, inv = inv_sh;
    const float4 g  = ((const float4*)gamma)[tid];
    const float4 bb = ((const float4*)beta)[tid];
    float4 o;
    o.x = (v.x - mu) * inv * g.x + bb.x;
    o.y = (v.y - mu) * inv * g.y + bb.y;
    o.z = (v.z - mu) * inv * g.z + bb.z;
    o.w = (v.w - mu) * inv * g.w + bb.w;
    ((float4*)(out + (size_t)row * kD))[tid] = o;
}

// ---------------------------------------------------------------------------
// Workspace layout (64 MB peak, aliasing is stream-ordered-safe):
//   [0,   8MB)  Xb bf16
//   [8,  16MB)  Wb bf16 wq|wk|wv|wo
//   [16, 40MB)  QKV bf16 Q|K|V  (Q pre-scaled by 0.125*log2e)
//   [40, 48MB)  Ctx bf16
//   [48, 64MB)  VT bf16 [32][64][2048]; ALIASES R (written strictly later)
// ---------------------------------------------------------------------------
extern "C" void kernel_launch(void* const* d_in, const int* in_sizes, int n_in,
                              void* d_out, int out_size, void* d_ws, size_t ws_size,
                              hipStream_t stream) {
    const float* x     = (const float*)d_in[0];
    const float* wq    = (const float*)d_in[1];
    const float* wk    = (const float*)d_in[2];
    const float* wv    = (const float*)d_in[3];
    const float* wo    = (const float*)d_in[4];
    const float* gamma = (const float*)d_in[5];
    const float* beta  = (const float*)d_in[6];
    float* out = (float*)d_out;

    char* ws = (char*)d_ws;
    unsigned short* Xb  = (unsigned short*)(ws);
    unsigned short* Wb  = (unsigned short*)(ws + (8u  << 20));
    unsigned short* QKV = (unsigned short*)(ws + (16u << 20));
    unsigned short* Qb  = QKV;
    unsigned short* Kb  = QKV + (size_t)kBS * kD;
    unsigned short* Vb  = QKV + (size_t)2 * kBS * kD;
    unsigned short* Ctx = (unsigned short*)(ws + (40u << 20));
    unsigned short* VT  = (unsigned short*)(ws + (48u << 20));
    float* R            = (float*)(ws + (48u << 20));  // aliases VT

    convert_kernel<<<8192, 256, 0, stream>>>(x, wq, wk, wv, wo, Xb, Wb);

    gemm_nt<0><<<dim3(kD / 128, kBS / 128, 3), 256, 0, stream>>>(
        Xb, Wb, QKV, nullptr, kBS, kD, kD);

    stats_vt_kernel<<<1024, 128, 0, stream>>>(Qb, Kb, Vb, VT);

    ctx_kernel<<<1024, 128, 0, stream>>>(Qb, Kb, VT, Ctx);

    gemm_nt<1><<<dim3(kD / 128, kBS / 128, 1), 256, 0, stream>>>(
        Ctx, Wb + (size_t)3 * kD * kD, R, x, kBS, kD, kD);

    ln_kernel<<<kBS, 256, 0, stream>>>(R, gamma, beta, out);
}